// Round 9
// baseline (1063.192 us; speedup 1.0000x reference)
//
#include <hip/hip_runtime.h>

typedef unsigned short u16;
typedef short bf8 __attribute__((ext_vector_type(8)));
typedef short bf4 __attribute__((ext_vector_type(4)));
typedef float f4 __attribute__((ext_vector_type(4)));
typedef _Float16 h2v __attribute__((ext_vector_type(2)));
typedef __fp16 g2v __attribute__((ext_vector_type(2)));
typedef unsigned int u4v __attribute__((ext_vector_type(4)));

#define N_NODES 20000
#define N_EDGES 320000
#define NGRAPH 40
#define NPG 500
#define KTOP 250
#define NSEG (N_NODES * 8)

// parms arena offsets (u16 elements)
#define P_CONV_BIAS 0
#define P_POOL_W    768
#define P_POOL_ROOT 6912
#define P_POOL_BIAS 7680
#define P_FC1_W     7688
#define P_FC1_B     204296
#define P_W_IH      204552
#define P_B_IH      466696
#define P_B_HH      467720
#define P_FC2_W     468744
#define P_FC2_B     469256
#define P_TOTAL     469264

// k_prep range boundaries (flat thread index)
#define PR_A0 0
#define PR_B0 469264                      // + P_TOTAL
#define PR_C0 (PR_B0 + 640000)            // + N_NODES*32 stage-x octets
#define PR_D0 (PR_C0 + 1769472)           // + 3*36*256*64 transpose elems
#define PR_END (PR_D0 + 131072)           // + 32*1024*4 whh4 elems

__device__ __forceinline__ float b2f(u16 u) {
    union { unsigned int i; float f; } v; v.i = ((unsigned int)u) << 16; return v.f;
}
__device__ __forceinline__ u16 f2b(float f) {
    union { float f; unsigned int i; } v; v.f = f;
    unsigned int x = v.i;
    return (u16)((x + 0x7fffu + ((x >> 16) & 1u)) >> 16);
}
__device__ __forceinline__ float wred(float s) {
    #pragma unroll
    for (int off = 32; off > 0; off >>= 1) s += __shfl_down(s, off);
    return s;
}
__device__ __forceinline__ float fdot2u(unsigned a, unsigned b, float c) {
#if __has_builtin(__builtin_amdgcn_fdot2)
    union { unsigned u; h2v h; } ua, ub; ua.u = a; ub.u = b;
    return __builtin_amdgcn_fdot2(ua.h, ub.h, c, false);
#else
    union { unsigned u; g2v h; } ua, ub; ua.u = a; ub.u = b;
    return c + (float)ua.h[0] * (float)ub.h[0] + (float)ua.h[1] * (float)ub.h[1];
#endif
}
__device__ __forceinline__ unsigned packh2(float a, float b) {
    g2v h = __builtin_amdgcn_cvt_pkrtz(a, b);
    union { g2v h; unsigned u; } v; v.h = h; return v.u;
}
// fast activations (v_exp based); |err| ~1e-6, far under output tolerance
__device__ __forceinline__ float sigm_f(float x) {
    return 1.0f / (1.0f + __expf(-x));
}
__device__ __forceinline__ float tanh_f(float x) {
    return 1.0f - 2.0f / (1.0f + __expf(2.0f * x));
}

// ---------------- init: zero flag + cnt + ctr ----------------
__global__ void k_init(unsigned int* __restrict__ flag, unsigned int* __restrict__ cnt,
                       unsigned int* __restrict__ ctr) {
    int i = blockIdx.x * 256 + threadIdx.x;
    if (i < 64) flag[i] = 0u;
    if (i < NSEG) { cnt[i] = 0u; ctr[i] = 0u; }
}

// ---------------- dtype detection (parallel) ----------------
__global__ void k_detect1(const u16* __restrict__ xr, int n, unsigned int* __restrict__ fb) {
    unsigned int local = 0;
    for (int i = blockIdx.x * 256 + threadIdx.x; i < n; i += 64 * 256) {
        unsigned int u = xr[i];
        if (((u >> 7) & 0xFFu) == 0xFFu) local++;
    }
    local = (unsigned int)wred((float)local);
    if ((threadIdx.x & 63) == 0 && local) atomicAdd(&fb[1], local);
}

__device__ __forceinline__ u16 load_cvt(const void* src, size_t i, bool f32) {
    return f32 ? f2b(((const float*)src)[i]) : ((const u16*)src)[i];
}

// ---------------- degree counts (+ flag finalize, was k_detect2) ----------------
__global__ void k_count(const int* __restrict__ dst, const int* __restrict__ et,
                        unsigned int* __restrict__ cnt, unsigned int* __restrict__ fb) {
    int e = blockIdx.x * 256 + threadIdx.x;
    if (e == 0) fb[0] = (fb[1] > 8u) ? 1u : 0u;
    if (e < N_EDGES) {
        unsigned d = (unsigned)dst[e]; if (d >= N_NODES) d = 0;
        unsigned r = (unsigned)et[e] & 7u;
        atomicAdd(&cnt[d * 8 + r], 1u);
    }
}

// ---------------- prefix scan (exclusive) over cnt[160000] ----------------
__global__ void k_scan1(const unsigned int* __restrict__ cnt, unsigned int* __restrict__ seg,
                        unsigned int* __restrict__ bsum) {
    __shared__ unsigned int s[256];
    int t = threadIdx.x, i = blockIdx.x * 256 + t;
    unsigned int v = (i < NSEG) ? cnt[i] : 0u;
    s[t] = v;
    __syncthreads();
    for (int off = 1; off < 256; off <<= 1) {
        unsigned int add = (t >= off) ? s[t - off] : 0u;
        __syncthreads();
        s[t] += add;
        __syncthreads();
    }
    if (i < NSEG) seg[i] = s[t] - v;
    if (t == 255) bsum[blockIdx.x] = s[255];
}
__global__ void k_scan2(unsigned int* __restrict__ bsum, int nb) {
    __shared__ unsigned int s[1024];
    int t = threadIdx.x;
    unsigned int v = (t < nb) ? bsum[t] : 0u;
    s[t] = v;
    __syncthreads();
    for (int off = 1; off < 1024; off <<= 1) {
        unsigned int add = (t >= off) ? s[t - off] : 0u;
        __syncthreads();
        s[t] += add;
        __syncthreads();
    }
    if (t < nb) bsum[t] = s[t] - v;
}
__global__ void k_scan3(unsigned int* __restrict__ seg, const unsigned int* __restrict__ bsum) {
    int i = blockIdx.x * 256 + threadIdx.x;
    if (i < NSEG) seg[i] += bsum[i >> 8];
    if (i == 0) seg[NSEG] = N_EDGES;
}
// place edges into (dst,rel)-sorted order; skey = chunk-local src | (rel<<16)
// inv eliminated: weight computed inline from final cnt
__global__ void k_place(const int* __restrict__ src, const int* __restrict__ dst,
                        const int* __restrict__ et, const unsigned int* __restrict__ seg,
                        unsigned int* __restrict__ ctr, const unsigned int* __restrict__ cnt,
                        unsigned int* __restrict__ skey, float* __restrict__ sw, int cap) {
    int e = blockIdx.x * 256 + threadIdx.x;
    if (e >= N_EDGES) return;
    unsigned s = (unsigned)src[e]; if (s >= N_NODES) s = 0;
    unsigned d = (unsigned)dst[e]; if (d >= N_NODES) d = 0;
    unsigned r = (unsigned)et[e] & 7u;
    unsigned key = d * 8 + r;
    unsigned pos = seg[key] + atomicAdd(&ctr[key], 1u);
    unsigned base = (d / (unsigned)cap) * (unsigned)cap;   // chunks are whole graphs
    unsigned sl = s - base;
    if (sl >= (unsigned)cap) sl = 0u;            // defensive: keep in-bounds
    skey[pos] = sl | (r << 16);
    unsigned c = cnt[key];
    sw[pos] = 1.0f / (float)(c < 1u ? 1u : c);
}

// ---------------- fused one-shot prep: cvt_all | stage_x | transpose2 | whh4 -----
// one dispatch, ranges partitioned by flat index (was 4 dispatches)
__global__ void k_prep(const void* conv_bias, const void* pool_W, const void* pool_root,
                       const void* pool_bias, const void* fc1_W, const void* fc1_b,
                       const void* W_ih, const void* b_ih, const void* b_hh,
                       const void* fc2_W, const void* fc2_b,
                       const void* __restrict__ x, const void* __restrict__ conv_W,
                       const void* __restrict__ conv_root, const void* __restrict__ W_hh,
                       u16* __restrict__ parms, u16* __restrict__ xc,
                       u16* __restrict__ Wt, unsigned int* __restrict__ whh4,
                       const unsigned int* __restrict__ flag) {
    int idx = blockIdx.x * 256 + threadIdx.x;
    bool f32 = (*flag != 0u);
    if (idx < PR_B0) {                                   // param canonicalization
        int i = idx;
        u16 v;
        if      (i < P_CONV_BIAS + 768)    v = load_cvt(conv_bias, i - P_CONV_BIAS, f32);
        else if (i < P_POOL_W + 6144)      v = load_cvt(pool_W,    i - P_POOL_W, f32);
        else if (i < P_POOL_ROOT + 768)    v = load_cvt(pool_root, i - P_POOL_ROOT, f32);
        else if (i < P_POOL_BIAS + 1)      v = load_cvt(pool_bias, i - P_POOL_BIAS, f32);
        else if (i < P_FC1_W && i >= P_POOL_BIAS) return;   // alignment gap
        else if (i < P_FC1_W + 196608)     v = load_cvt(fc1_W,    i - P_FC1_W, f32);
        else if (i < P_FC1_B + 256)        v = load_cvt(fc1_b,    i - P_FC1_B, f32);
        else if (i < P_W_IH + 262144)      v = load_cvt(W_ih,     i - P_W_IH, f32);
        else if (i < P_B_IH + 1024)        v = load_cvt(b_ih,     i - P_B_IH, f32);
        else if (i < P_B_HH + 1024)        v = load_cvt(b_hh,     i - P_B_HH, f32);
        else if (i < P_FC2_W + 512)        v = load_cvt(fc2_W,    i - P_FC2_W, f32);
        else if (i < P_FC2_B + 2)          v = load_cvt(fc2_b,    i - P_FC2_B, f32);
        else return;
        parms[i] = v;
    } else if (idx < PR_C0) {                            // stage x -> xc[:,512:768]
        int i = idx - PR_B0;
        int n = i >> 5, o = (i & 31) * 8;
        bf8 v;
        if (f32) {
            const float* s = (const float*)x + (size_t)n * 256 + o;
            #pragma unroll
            for (int c = 0; c < 8; ++c) v[c] = (short)f2b(s[c]);
        } else {
            v = *(const bf8*)((const u16*)x + (size_t)n * 256 + o);
        }
        *(bf8*)(xc + (size_t)n * 768 + 512 + o) = v;
    } else if (idx < PR_D0) {                            // conv weight transpose
        int i = idx - PR_C0;
        int kk = i & 63;
        int n = (i >> 6) & 255;
        int lc = i >> 14;            // l*36 + ck
        int l = lc / 36, ck = lc % 36;
        int k = ck * 64 + kk;
        u16 v;
        if (k < 2048) {
            int r = k >> 8, ii = k & 255;
            v = load_cvt(conv_W, ((size_t)((l * 8 + r) * 256 + ii)) * 256 + n, f32);
        } else {
            int ii = k - 2048;
            v = load_cvt(conv_root, ((size_t)(l * 256 + ii)) * 256 + n, f32);
        }
        Wt[i] = v;
    } else if (idx < PR_END) {                           // W_hh pack
        int i = idx - PR_D0;
        int c = i & 3, j = (i >> 2) & 1023, i4 = i >> 12;
        int i2 = i4 * 4 + c;
        float a, b;
        if (f32) {
            a = ((const float*)W_hh)[j * 256 + 2 * i2];
            b = ((const float*)W_hh)[j * 256 + 2 * i2 + 1];
        } else {
            a = b2f(((const u16*)W_hh)[j * 256 + 2 * i2]);
            b = b2f(((const u16*)W_hh)[j * 256 + 2 * i2 + 1]);
        }
        whh4[i] = packh2(a, b);
    }
}

// ---------------- dense per-relation transform over a node chunk ----------------
// Hall[rg][local][256] = X[n0+local] @ W_rg,  rg=0..7 rels, 8 = root.
// grid (ceil(chnc/64), 9); 4 waves; wave w owns 64 output cols. Pure dense GEMM.
__launch_bounds__(256, 3)
__global__ void k_layer2(const u16* __restrict__ xprev,      // stride 768
                         const u16* __restrict__ WtL,        // [36][256][64]
                         u16* __restrict__ Hall, int n0, int chnc) {
    __shared__ u16 As[64 * 264];
    int m0 = n0 + blockIdx.x * 64;
    int rg = blockIdx.y;
    int nend = n0 + chnc;
    int wave = threadIdx.x >> 6, lane = threadIdx.x & 63;
    int mrow = lane & 15, quad = lane >> 4;
    int nbase = wave * 64;

    // stage A tile [64][256] (dense, coalesced; zero-pad past chunk)
    {
        int row = threadIdx.x >> 2, sg = threadIdx.x & 3;
        int gm = m0 + row;
        u16* dstp = As + row * 264 + sg * 64;
        if (gm < nend) {
            const u16* srcp = xprev + (size_t)gm * 768 + sg * 64;
            #pragma unroll
            for (int c = 0; c < 8; ++c)
                *(bf8*)(dstp + c * 8) = *(const bf8*)(srcp + c * 8);
        } else {
            bf8 z = {0, 0, 0, 0, 0, 0, 0, 0};
            #pragma unroll
            for (int c = 0; c < 8; ++c) *(bf8*)(dstp + c * 8) = z;
        }
    }
    __syncthreads();

    f4 acc[4][4];
    #pragma unroll
    for (int nt = 0; nt < 4; ++nt)
        #pragma unroll
        for (int mh = 0; mh < 4; ++mh) acc[nt][mh] = (f4){0.0f, 0.0f, 0.0f, 0.0f};

    const u16* WtR = WtL + (size_t)(rg * 4) * 16384;   // ck = rg*4 + c4 (rg==8 -> root)
    #pragma unroll
    for (int c4 = 0; c4 < 4; ++c4) {
        const u16* Bck = WtR + (size_t)c4 * 16384;
        #pragma unroll
        for (int ks = 0; ks < 2; ++ks) {
            bf8 a[4];
            #pragma unroll
            for (int mh = 0; mh < 4; ++mh)
                a[mh] = *(const bf8*)(As + (mh * 16 + mrow) * 264 + c4 * 64 + ks * 32 + quad * 8);
            #pragma unroll
            for (int nt = 0; nt < 4; ++nt) {
                bf8 b = *(const bf8*)(Bck + (size_t)(nbase + nt * 16 + mrow) * 64
                                      + ks * 32 + quad * 8);
                #pragma unroll
                for (int mh = 0; mh < 4; ++mh)
                    acc[nt][mh] = __builtin_amdgcn_mfma_f32_16x16x32_bf16(a[mh], b, acc[nt][mh], 0, 0, 0);
            }
        }
    }

    // epilogue: restage to LDS ([64 m][256 n] stride 264), coalesced b128 store
    __syncthreads();
    #pragma unroll
    for (int nt = 0; nt < 4; ++nt) {
        int col = nbase + nt * 16 + mrow;
        #pragma unroll
        for (int mh = 0; mh < 4; ++mh)
            #pragma unroll
            for (int v = 0; v < 4; ++v)
                As[(mh * 16 + quad * 4 + v) * 264 + col] = f2b(acc[nt][mh][v]);
    }
    __syncthreads();
    {
        int row = threadIdx.x >> 2, sg = threadIdx.x & 3;
        int gm = m0 + row;
        if (gm < nend) {
            u16* dst = Hall + ((size_t)rg * chnc + (gm - n0)) * 256 + sg * 64;
            const u16* srcp = As + row * 264 + sg * 64;
            #pragma unroll
            for (int c = 0; c < 8; ++c)
                *(bf8*)(dst + c * 8) = *(const bf8*)(srcp + c * 8);
        }
    }
}

// ---------------- edge gather over transformed features ----------------
__launch_bounds__(256)
__global__ void k_gather(const unsigned int* __restrict__ seg,
                         const unsigned int* __restrict__ skey,
                         const float* __restrict__ sw,
                         const u16* __restrict__ Hall,
                         const u16* __restrict__ bias,
                         u16* __restrict__ xc, int colbase, int n0, int chnc) {
    int nl = blockIdx.x * 4 + (threadIdx.x >> 6);
    if (nl >= chnc) return;
    int n = n0 + nl;
    int lane = threadIdx.x & 63;
    int c0 = lane * 4;
    unsigned e0 = seg[n * 8], e1 = seg[n * 8 + 8];
    float a0 = 0.0f, a1 = 0.0f, a2 = 0.0f, a3 = 0.0f;
    unsigned key = 0; float w = 0.0f;
    if (e0 < e1) { key = skey[e0]; w = sw[e0]; }
    for (unsigned e = e0; e < e1;) {
        unsigned kc = key; float wc = w;
        ++e;
        if (e < e1) { key = skey[e]; w = sw[e]; }   // prefetch next key while row load flies
        const u16* row = Hall + ((size_t)(kc >> 16) * chnc + (kc & 0xFFFFu)) * 256 + c0;
        bf4 v = *(const bf4*)row;
        a0 += wc * b2f((u16)v[0]);
        a1 += wc * b2f((u16)v[1]);
        a2 += wc * b2f((u16)v[2]);
        a3 += wc * b2f((u16)v[3]);
    }
    const u16* rr = Hall + ((size_t)8 * chnc + nl) * 256 + c0;
    bf4 rv = *(const bf4*)rr;
    float o0 = a0 + b2f((u16)rv[0]) + b2f(bias[c0 + 0]);
    float o1 = a1 + b2f((u16)rv[1]) + b2f(bias[c0 + 1]);
    float o2 = a2 + b2f((u16)rv[2]) + b2f(bias[c0 + 2]);
    float o3 = a3 + b2f((u16)rv[3]) + b2f(bias[c0 + 3]);
    bf4 o;
    o[0] = (short)f2b(o0 > 0.0f ? o0 : 0.0f);
    o[1] = (short)f2b(o1 > 0.0f ? o1 : 0.0f);
    o[2] = (short)f2b(o2 > 0.0f ? o2 : 0.0f);
    o[3] = (short)f2b(o3 > 0.0f ? o3 : 0.0f);
    *(bf4*)(xc + (size_t)n * 768 + colbase + c0) = o;
}

// ---------------- pool scorer: one wave per node, all 9 dots fused ----------------
__launch_bounds__(256)
__global__ void k_pool(const u16* __restrict__ xc, const u16* __restrict__ parms,
                       float* __restrict__ p, float* __restrict__ score) {
    int n = blockIdx.x * 4 + (threadIdx.x >> 6);
    if (n >= N_NODES) return;
    int lane = threadIdx.x & 63;
    const u16* xr = xc + (size_t)n * 768;
    float acc[9];
    #pragma unroll
    for (int rr = 0; rr < 9; ++rr) acc[rr] = 0.0f;
    #pragma unroll
    for (int q = 0; q < 12; ++q) {
        int f = lane + 64 * q;
        float xv = b2f(xr[f]);
        #pragma unroll
        for (int rr = 0; rr < 8; ++rr)
            acc[rr] += xv * b2f(parms[P_POOL_W + rr * 768 + f]);
        acc[8] += xv * b2f(parms[P_POOL_ROOT + f]);
    }
    #pragma unroll
    for (int rr = 0; rr < 9; ++rr) acc[rr] = wred(acc[rr]);
    if (lane == 0) {
        #pragma unroll
        for (int rr = 0; rr < 8; ++rr) p[rr * N_NODES + n] = acc[rr];
        score[n] = acc[8] + b2f(parms[P_POOL_BIAS]);
    }
}
__global__ void k_scatter_pool(const int* __restrict__ src, const int* __restrict__ dst,
                               const int* __restrict__ et, const unsigned int* __restrict__ cnt,
                               const float* __restrict__ p, float* __restrict__ score) {
    int e = blockIdx.x * 256 + threadIdx.x;
    if (e >= N_EDGES) return;
    int r = et[e] & 7;
    unsigned s = (unsigned)src[e]; if (s >= N_NODES) s = 0;
    unsigned d = (unsigned)dst[e]; if (d >= N_NODES) d = 0;
    unsigned c = cnt[d * 8 + r];
    float iv = 1.0f / (float)(c < 1u ? 1u : c);
    atomicAdd(&score[d], iv * p[r * N_NODES + s]);
}

// ---------------- fused tail: per-graph sort -> readout -> fc1 -> gx ----------
// block g does the whole per-graph chain in LDS (was 4 dispatches:
// k_sort, k_readout(40x12), k_fc1, k_gx). Only gx goes back to global.
__launch_bounds__(256)
__global__ void k_tail(const float* __restrict__ score, const u16* __restrict__ xc,
                       const u16* __restrict__ parms, float* __restrict__ gx) {
    __shared__ unsigned long long keys[512];
    __shared__ float vals[512];
    __shared__ unsigned int sidx[KTOP];
    __shared__ float sv[KTOP];
    __shared__ float part[256];
    __shared__ float rro[768];
    __shared__ float h1s[256];
    int g = blockIdx.x, tid = threadIdx.x;
    int wave = tid >> 6, lane = tid & 63;
    // ---- phase 1: bitonic top-K sort (identical to k_sort) ----
    for (int i = tid; i < 512; i += 256) {
        unsigned long long key;
        float v = 0.0f;
        if (i < NPG) {
            v = tanhf(score[g * NPG + i]);
            unsigned int u = __float_as_uint(v);
            u = (u & 0x80000000u) ? ~u : (u | 0x80000000u);
            u = ~u;
            key = ((unsigned long long)u << 32) | (unsigned int)i;
        } else {
            key = 0xFFFFFFFFFFFFFFFFull;
        }
        keys[i] = key;
        vals[i] = v;
    }
    __syncthreads();
    for (int k = 2; k <= 512; k <<= 1)
        for (int j = k >> 1; j > 0; j >>= 1) {
            for (int i = tid; i < 512; i += 256) {
                int ixj = i ^ j;
                if (ixj > i) {
                    bool up = ((i & k) == 0);
                    unsigned long long a = keys[i], b = keys[ixj];
                    if ((a > b) == up) { keys[i] = b; keys[ixj] = a; }
                }
            }
            __syncthreads();
        }
    if (tid < KTOP) {
        int idx = (int)(keys[tid] & 511u);
        sidx[tid] = (unsigned)idx;
        sv[tid] = vals[idx];
    }
    __syncthreads();
    // ---- phase 2: weighted readout (12 column-blocks of 64) ----
    int fl = tid & 63, ng = tid >> 6;
    for (int cb = 0; cb < 12; ++cb) {
        float acc = 0.0f;
        int f = cb * 64 + fl;
        for (int j = ng; j < KTOP; j += 4)
            acc += sv[j] * b2f(xc[(size_t)(g * NPG + sidx[j]) * 768 + f]);
        part[tid] = acc;
        __syncthreads();
        if (tid < 64)
            rro[cb * 64 + tid] = (part[tid] + part[64 + tid] + part[128 + tid]
                                  + part[192 + tid]) * (1.0f / (float)KTOP);
        __syncthreads();
    }
    // ---- phase 3: fc1 (wave-reduce per output, 64 outputs/wave) ----
    for (int o = wave; o < 256; o += 4) {
        const u16* w = parms + P_FC1_W + (size_t)o * 768;
        float s = 0.0f;
        #pragma unroll
        for (int q = 0; q < 12; ++q) { int f = lane + 64 * q; s += rro[f] * b2f(w[f]); }
        s = wred(s);
        if (lane == 0) {
            s += b2f(parms[P_FC1_B + o]);
            h1s[o] = s > 0.0f ? s : 0.0f;
        }
    }
    __syncthreads();
    // ---- phase 4: gx (256 outputs/wave) ----
    for (int j = wave; j < 1024; j += 4) {
        const u16* w = parms + P_W_IH + (size_t)j * 256;
        float s = 0.0f;
        #pragma unroll
        for (int q = 0; q < 4; ++q) { int f = lane + 64 * q; s += h1s[f] * b2f(w[f]); }
        s = wred(s);
        if (lane == 0)
            gx[g * 1024 + j] = s + b2f(parms[P_B_IH + j]) + b2f(parms[P_B_HH + j]);
    }
}

// ---------------- sequential LSTM (round-3 variant, proven 107 us) ----------
// 5 attempts to beat this (reg/LDS/AGPR pinning, 2x multi-CU) all failed:
// the RA spills the 192 weight regs no matter what; single-CU L2 streaming of
// 512 KB/step (~80 B/cyc) is the floor; cross-XCD sync costs ~3.5 us/step.
__launch_bounds__(512, 1)
__global__ void k_lstm(const float* __restrict__ gx, const unsigned int* __restrict__ whh4,
                       const u16* __restrict__ parms, void* __restrict__ out,
                       const unsigned int* __restrict__ flag) {
    __shared__ float hs[256];
    __shared__ unsigned int hs2[128];
    __shared__ float gs[1024];
    __shared__ float red[2];
    int tid = threadIdx.x;
    int j0 = tid, j1 = tid + 512;
    u4v wa[24], wb[24];
    #pragma unroll
    for (int q = 0; q < 24; ++q) {
        wa[q] = *(const u4v*)(whh4 + (((size_t)q * 1024) + j0) * 4);
        wb[q] = *(const u4v*)(whh4 + (((size_t)q * 1024) + j1) * 4);
    }
    asm volatile("" : "+v"(wa[0]), "+v"(wa[1]), "+v"(wa[2]), "+v"(wa[3]),
                      "+v"(wa[4]), "+v"(wa[5]), "+v"(wa[6]), "+v"(wa[7]),
                      "+v"(wa[8]), "+v"(wa[9]), "+v"(wa[10]), "+v"(wa[11]),
                      "+v"(wa[12]), "+v"(wa[13]), "+v"(wa[14]), "+v"(wa[15]),
                      "+v"(wa[16]), "+v"(wa[17]), "+v"(wa[18]), "+v"(wa[19]),
                      "+v"(wa[20]), "+v"(wa[21]), "+v"(wa[22]), "+v"(wa[23]));
    asm volatile("" : "+v"(wb[0]), "+v"(wb[1]), "+v"(wb[2]), "+v"(wb[3]),
                      "+v"(wb[4]), "+v"(wb[5]), "+v"(wb[6]), "+v"(wb[7]),
                      "+v"(wb[8]), "+v"(wb[9]), "+v"(wb[10]), "+v"(wb[11]),
                      "+v"(wb[12]), "+v"(wb[13]), "+v"(wb[14]), "+v"(wb[15]),
                      "+v"(wb[16]), "+v"(wb[17]), "+v"(wb[18]), "+v"(wb[19]),
                      "+v"(wb[20]), "+v"(wb[21]), "+v"(wb[22]), "+v"(wb[23]));
    if (tid < 256) hs[tid] = 0.0f;
    if (tid < 128) hs2[tid] = 0u;
    float c = 0.0f;
    __syncthreads();
    for (int t = 0; t < NGRAPH; ++t) {
        float g0 = gx[t * 1024 + j0];
        float g1 = gx[t * 1024 + j1];
        #pragma unroll
        for (int q = 0; q < 24; ++q) {
            #pragma unroll
            for (int cc = 0; cc < 4; ++cc) {
                unsigned h2 = hs2[q * 4 + cc];
                g0 = fdot2u(wa[q][cc], h2, g0);
                g1 = fdot2u(wb[q][cc], h2, g1);
            }
        }
        #pragma unroll 2
        for (int q = 24; q < 32; ++q) {
            u4v v0 = *(const u4v*)(whh4 + (((size_t)q * 1024) + j0) * 4);
            u4v v1 = *(const u4v*)(whh4 + (((size_t)q * 1024) + j1) * 4);
            #pragma unroll
            for (int cc = 0; cc < 4; ++cc) {
                unsigned h2 = hs2[q * 4 + cc];
                g0 = fdot2u(v0[cc], h2, g0);
                g1 = fdot2u(v1[cc], h2, g1);
            }
        }
        gs[j0] = g0;
        gs[j1] = g1;
        __syncthreads();
        if (tid < 256) {
            float gi = sigm_f(gs[tid]);
            float gf = sigm_f(gs[256 + tid]);
            float gg = tanh_f(gs[512 + tid]);
            float go = sigm_f(gs[768 + tid]);
            c = gf * c + gi * gg;
            float h = go * tanh_f(c);
            hs[tid] = h;
            float ho = __shfl(h, (tid & 63) ^ 1);
            if (!(tid & 1)) hs2[tid >> 1] = packh2(h, ho);
        }
        __syncthreads();
    }
    if (tid < 128) {
        int cls = tid >> 6, lane = tid & 63;
        float s = 0.0f;
        #pragma unroll
        for (int q = 0; q < 4; ++q) {
            int d = lane + 64 * q;
            s += hs[d] * b2f(parms[P_FC2_W + cls * 256 + d]);
        }
        s = wred(s);
        if (lane == 0) red[cls] = s + b2f(parms[P_FC2_B + cls]);
    }
    __syncthreads();
    if (tid == 0) {
        float l0 = red[0], l1 = red[1];
        float m = fmaxf(l0, l1);
        float lse = m + logf(expf(l0 - m) + expf(l1 - m));
        float o0 = l0 - lse, o1 = l1 - lse;
        if (*flag) { ((float*)out)[0] = o0; ((float*)out)[1] = o1; }
        else       { ((u16*)out)[0] = f2b(o0); ((u16*)out)[1] = f2b(o1); }
    }
}

// ---------------- workspace plan (Hall sized by chunk cap) ----------------
struct WS {
    unsigned int* flag; unsigned int* cnt; unsigned int* seg; unsigned int* ctr;
    unsigned int* skey; float* sw; unsigned int* bsum;
    u16* Wt2; u16* xc; u16* Hall; float* p; float* score;
    float* gx; unsigned int* whh4; u16* parms;
    size_t need;
};
static WS plan(char* base, int cap) {
    WS w; size_t off = 0;
    auto take = [&](size_t bytes) -> char* {
        char* p = base + off; off += (bytes + 255) & ~(size_t)255; return p;
    };
    w.flag    = (unsigned int*)take(256);
    w.cnt     = (unsigned int*)take((size_t)NSEG * 4);
    w.seg     = (unsigned int*)take((size_t)(NSEG + 1) * 4);
    w.ctr     = (unsigned int*)take((size_t)NSEG * 4);
    w.skey    = (unsigned int*)take((size_t)N_EDGES * 4);
    w.sw      = (float*)take((size_t)N_EDGES * 4);
    w.bsum    = (unsigned int*)take(1024 * 4);
    w.Wt2     = (u16*)take((size_t)3 * 36 * 256 * 64 * 2);
    w.xc      = (u16*)take((size_t)N_NODES * 768 * 2);
    w.Hall    = (u16*)take((size_t)9 * cap * 256 * 2);
    w.p       = (float*)take((size_t)8 * N_NODES * 4);
    w.score   = (float*)take((size_t)N_NODES * 4);
    w.gx      = (float*)take((size_t)NGRAPH * 1024 * 4);
    w.whh4    = (unsigned int*)take((size_t)32 * 1024 * 4 * 4);
    w.parms   = (u16*)take((size_t)P_TOTAL * 2);
    w.need = off;
    return w;
}

extern "C" void kernel_launch(void* const* d_in, const int* in_sizes, int n_in,
                              void* d_out, int out_size, void* d_ws, size_t ws_size,
                              hipStream_t stream) {
    (void)in_sizes; (void)n_in; (void)out_size;
    const void* x        = d_in[0];
    const int* edge_index= (const int*)d_in[1];
    const int* edge_attr = (const int*)d_in[2];
    const void* conv_W   = d_in[4];
    const void* conv_root= d_in[5];
    const void* conv_bias= d_in[6];
    const void* pool_W   = d_in[7];
    const void* pool_root= d_in[8];
    const void* pool_bias= d_in[9];
    const void* fc1_W    = d_in[10];
    const void* fc1_b    = d_in[11];
    const void* W_ih     = d_in[12];
    const void* W_hh     = d_in[13];
    const void* b_ih     = d_in[14];
    const void* b_hh     = d_in[15];
    const void* fc2_W    = d_in[16];
    const void* fc2_b    = d_in[17];

    const int* e_src = edge_index;
    const int* e_dst = edge_index + N_EDGES;

    // chunk cap (multiple of NPG so chunks are whole graphs); unequal last chunk ok
    if (ws_size == 0) ws_size = (size_t)64 << 20;
    int cap = 500;
    {
        const int ladder[9] = {20000, 10000, 7000, 5000, 4000, 2500, 2000, 1000, 500};
        for (int i = 0; i < 9; ++i) {
            if (plan((char*)d_ws, ladder[i]).need <= ws_size) { cap = ladder[i]; break; }
        }
    }
    WS w = plan((char*)d_ws, cap);

    k_init<<<(NSEG + 255) / 256, 256, 0, stream>>>(w.flag, w.cnt, w.ctr);
    k_detect1<<<64, 256, 0, stream>>>((const u16*)x, 1 << 18, w.flag);
    k_count<<<1250, 256, 0, stream>>>(e_dst, edge_attr, w.cnt, w.flag);
    k_scan1<<<625, 256, 0, stream>>>(w.cnt, w.seg, w.bsum);
    k_scan2<<<1, 1024, 0, stream>>>(w.bsum, 625);
    k_scan3<<<(NSEG + 255) / 256, 256, 0, stream>>>(w.seg, w.bsum);
    k_place<<<1250, 256, 0, stream>>>(e_src, e_dst, edge_attr, w.seg, w.ctr, w.cnt,
                                      w.skey, w.sw, cap);

    k_prep<<<(PR_END + 255) / 256, 256, 0, stream>>>(
        conv_bias, pool_W, pool_root, pool_bias, fc1_W, fc1_b,
        W_ih, b_ih, b_hh, fc2_W, fc2_b,
        x, conv_W, conv_root, W_hh,
        w.parms, w.xc, w.Wt2, w.whh4, w.flag);

    for (int l = 0; l < 3; ++l) {
        const u16* xprev = w.xc + (l == 0 ? 512 : (l - 1) * 256);
        const u16* WtL = w.Wt2 + (size_t)l * 36 * 16384;
        const u16* bias = w.parms + P_CONV_BIAS + l * 256;
        for (int n0 = 0; n0 < N_NODES; n0 += cap) {
            int chnc = N_NODES - n0 < cap ? N_NODES - n0 : cap;
            int tiles = (chnc + 63) / 64;
            k_layer2<<<dim3(tiles, 9), 256, 0, stream>>>(xprev, WtL, w.Hall, n0, chnc);
            k_gather<<<(chnc + 3) / 4, 256, 0, stream>>>(w.seg, w.skey, w.sw, w.Hall,
                                                         bias, w.xc, l * 256, n0, chnc);
        }
    }

    k_pool<<<5000, 256, 0, stream>>>(w.xc, w.parms, w.p, w.score);
    k_scatter_pool<<<1250, 256, 0, stream>>>(e_src, e_dst, edge_attr, w.cnt, w.p, w.score);
    k_tail<<<NGRAPH, 256, 0, stream>>>(w.score, w.xc, w.parms, w.gx);
    k_lstm<<<1, 512, 0, stream>>>(w.gx, w.whh4, w.parms, d_out, w.flag);
}

// Round 10
// 686.862 us; speedup vs baseline: 1.5479x; 1.5479x over previous
//
#include <hip/hip_runtime.h>

typedef unsigned short u16;
typedef short bf8 __attribute__((ext_vector_type(8)));
typedef short bf4 __attribute__((ext_vector_type(4)));
typedef float f4 __attribute__((ext_vector_type(4)));
typedef _Float16 h2v __attribute__((ext_vector_type(2)));
typedef __fp16 g2v __attribute__((ext_vector_type(2)));
typedef unsigned int u4v __attribute__((ext_vector_type(4)));

#define N_NODES 20000
#define N_EDGES 320000
#define NGRAPH 40
#define NPG 500
#define KTOP 250
#define NSEG (N_NODES * 8)

// parms arena offsets (u16 elements)
#define P_CONV_BIAS 0
#define P_POOL_W    768
#define P_POOL_ROOT 6912
#define P_POOL_BIAS 7680
#define P_FC1_W     7688
#define P_FC1_B     204296
#define P_W_IH      204552
#define P_B_IH      466696
#define P_B_HH      467720
#define P_FC2_W     468744
#define P_FC2_B     469256
#define P_TOTAL     469264

// k_prep range boundaries (flat thread index)
#define PR_B0 469264                      // + P_TOTAL
#define PR_C0 (PR_B0 + 640000)            // + N_NODES*32 stage-x octets
#define PR_D0 (PR_C0 + 1769472)           // + 3*36*256*64 transpose elems
#define PR_END (PR_D0 + 131072)           // + 32*1024*4 whh4 elems

__device__ __forceinline__ float b2f(u16 u) {
    union { unsigned int i; float f; } v; v.i = ((unsigned int)u) << 16; return v.f;
}
__device__ __forceinline__ u16 f2b(float f) {
    union { float f; unsigned int i; } v; v.f = f;
    unsigned int x = v.i;
    return (u16)((x + 0x7fffu + ((x >> 16) & 1u)) >> 16);
}
__device__ __forceinline__ float wred(float s) {
    #pragma unroll
    for (int off = 32; off > 0; off >>= 1) s += __shfl_down(s, off);
    return s;
}
__device__ __forceinline__ float fdot2u(unsigned a, unsigned b, float c) {
#if __has_builtin(__builtin_amdgcn_fdot2)
    union { unsigned u; h2v h; } ua, ub; ua.u = a; ub.u = b;
    return __builtin_amdgcn_fdot2(ua.h, ub.h, c, false);
#else
    union { unsigned u; g2v h; } ua, ub; ua.u = a; ub.u = b;
    return c + (float)ua.h[0] * (float)ub.h[0] + (float)ua.h[1] * (float)ub.h[1];
#endif
}
__device__ __forceinline__ unsigned packh2(float a, float b) {
    g2v h = __builtin_amdgcn_cvt_pkrtz(a, b);
    union { g2v h; unsigned u; } v; v.h = h; return v.u;
}
// fast activations (v_exp based); |err| ~1e-6, far under output tolerance
__device__ __forceinline__ float sigm_f(float x) {
    return 1.0f / (1.0f + __expf(-x));
}
__device__ __forceinline__ float tanh_f(float x) {
    return 1.0f - 2.0f / (1.0f + __expf(2.0f * x));
}

// ---------------- init: zero flag + cnt + ctr ----------------
__global__ void k_init(unsigned int* __restrict__ flag, unsigned int* __restrict__ cnt,
                       unsigned int* __restrict__ ctr) {
    int i = blockIdx.x * 256 + threadIdx.x;
    if (i < 64) flag[i] = 0u;
    if (i < NSEG) { cnt[i] = 0u; ctr[i] = 0u; }
}

// ---------------- dtype detection (parallel) ----------------
__global__ void k_detect1(const u16* __restrict__ xr, int n, unsigned int* __restrict__ fb) {
    unsigned int local = 0;
    for (int i = blockIdx.x * 256 + threadIdx.x; i < n; i += 64 * 256) {
        unsigned int u = xr[i];
        if (((u >> 7) & 0xFFu) == 0xFFu) local++;
    }
    local = (unsigned int)wred((float)local);
    if ((threadIdx.x & 63) == 0 && local) atomicAdd(&fb[1], local);
}

__device__ __forceinline__ u16 load_cvt(const void* src, size_t i, bool f32) {
    return f32 ? f2b(((const float*)src)[i]) : ((const u16*)src)[i];
}

// ---------------- degree counts (+ flag finalize, was k_detect2) ----------------
__global__ void k_count(const int* __restrict__ dst, const int* __restrict__ et,
                        unsigned int* __restrict__ cnt, unsigned int* __restrict__ fb) {
    int e = blockIdx.x * 256 + threadIdx.x;
    if (e == 0) fb[0] = (fb[1] > 8u) ? 1u : 0u;
    if (e < N_EDGES) {
        unsigned d = (unsigned)dst[e]; if (d >= N_NODES) d = 0;
        unsigned r = (unsigned)et[e] & 7u;
        atomicAdd(&cnt[d * 8 + r], 1u);
    }
}

// ---------------- prefix scan (exclusive) over cnt[160000] ----------------
__global__ void k_scan1(const unsigned int* __restrict__ cnt, unsigned int* __restrict__ seg,
                        unsigned int* __restrict__ bsum) {
    __shared__ unsigned int s[256];
    int t = threadIdx.x, i = blockIdx.x * 256 + t;
    unsigned int v = (i < NSEG) ? cnt[i] : 0u;
    s[t] = v;
    __syncthreads();
    for (int off = 1; off < 256; off <<= 1) {
        unsigned int add = (t >= off) ? s[t - off] : 0u;
        __syncthreads();
        s[t] += add;
        __syncthreads();
    }
    if (i < NSEG) seg[i] = s[t] - v;
    if (t == 255) bsum[blockIdx.x] = s[255];
}
__global__ void k_scan2(unsigned int* __restrict__ bsum, int nb) {
    __shared__ unsigned int s[1024];
    int t = threadIdx.x;
    unsigned int v = (t < nb) ? bsum[t] : 0u;
    s[t] = v;
    __syncthreads();
    for (int off = 1; off < 1024; off <<= 1) {
        unsigned int add = (t >= off) ? s[t - off] : 0u;
        __syncthreads();
        s[t] += add;
        __syncthreads();
    }
    if (t < nb) bsum[t] = s[t] - v;
}
__global__ void k_scan3(unsigned int* __restrict__ seg, const unsigned int* __restrict__ bsum) {
    int i = blockIdx.x * 256 + threadIdx.x;
    if (i < NSEG) seg[i] += bsum[i >> 8];
    if (i == 0) seg[NSEG] = N_EDGES;
}
// place edges into (dst,rel)-sorted order; skey = chunk-local src | (rel<<16)
// inv eliminated: weight computed inline from final cnt
__global__ void k_place(const int* __restrict__ src, const int* __restrict__ dst,
                        const int* __restrict__ et, const unsigned int* __restrict__ seg,
                        unsigned int* __restrict__ ctr, const unsigned int* __restrict__ cnt,
                        unsigned int* __restrict__ skey, float* __restrict__ sw, int cap) {
    int e = blockIdx.x * 256 + threadIdx.x;
    if (e >= N_EDGES) return;
    unsigned s = (unsigned)src[e]; if (s >= N_NODES) s = 0;
    unsigned d = (unsigned)dst[e]; if (d >= N_NODES) d = 0;
    unsigned r = (unsigned)et[e] & 7u;
    unsigned key = d * 8 + r;
    unsigned pos = seg[key] + atomicAdd(&ctr[key], 1u);
    unsigned base = (d / (unsigned)cap) * (unsigned)cap;   // chunks are whole graphs
    unsigned sl = s - base;
    if (sl >= (unsigned)cap) sl = 0u;            // defensive: keep in-bounds
    skey[pos] = sl | (r << 16);
    unsigned c = cnt[key];
    sw[pos] = 1.0f / (float)(c < 1u ? 1u : c);
}

// ---------------- fused one-shot prep: cvt_all | stage_x | transpose2 | whh4 -----
__global__ void k_prep(const void* conv_bias, const void* pool_W, const void* pool_root,
                       const void* pool_bias, const void* fc1_W, const void* fc1_b,
                       const void* W_ih, const void* b_ih, const void* b_hh,
                       const void* fc2_W, const void* fc2_b,
                       const void* __restrict__ x, const void* __restrict__ conv_W,
                       const void* __restrict__ conv_root, const void* __restrict__ W_hh,
                       u16* __restrict__ parms, u16* __restrict__ xc,
                       u16* __restrict__ Wt, unsigned int* __restrict__ whh4,
                       const unsigned int* __restrict__ flag) {
    int idx = blockIdx.x * 256 + threadIdx.x;
    bool f32 = (*flag != 0u);
    if (idx < PR_B0) {                                   // param canonicalization
        int i = idx;
        u16 v;
        if      (i < P_CONV_BIAS + 768)    v = load_cvt(conv_bias, i - P_CONV_BIAS, f32);
        else if (i < P_POOL_W + 6144)      v = load_cvt(pool_W,    i - P_POOL_W, f32);
        else if (i < P_POOL_ROOT + 768)    v = load_cvt(pool_root, i - P_POOL_ROOT, f32);
        else if (i < P_POOL_BIAS + 1)      v = load_cvt(pool_bias, i - P_POOL_BIAS, f32);
        else if (i < P_FC1_W && i >= P_POOL_BIAS) return;   // alignment gap
        else if (i < P_FC1_W + 196608)     v = load_cvt(fc1_W,    i - P_FC1_W, f32);
        else if (i < P_FC1_B + 256)        v = load_cvt(fc1_b,    i - P_FC1_B, f32);
        else if (i < P_W_IH + 262144)      v = load_cvt(W_ih,     i - P_W_IH, f32);
        else if (i < P_B_IH + 1024)        v = load_cvt(b_ih,     i - P_B_IH, f32);
        else if (i < P_B_HH + 1024)        v = load_cvt(b_hh,     i - P_B_HH, f32);
        else if (i < P_FC2_W + 512)        v = load_cvt(fc2_W,    i - P_FC2_W, f32);
        else if (i < P_FC2_B + 2)          v = load_cvt(fc2_b,    i - P_FC2_B, f32);
        else return;
        parms[i] = v;
    } else if (idx < PR_C0) {                            // stage x -> xc[:,512:768]
        int i = idx - PR_B0;
        int n = i >> 5, o = (i & 31) * 8;
        bf8 v;
        if (f32) {
            const float* s = (const float*)x + (size_t)n * 256 + o;
            #pragma unroll
            for (int c = 0; c < 8; ++c) v[c] = (short)f2b(s[c]);
        } else {
            v = *(const bf8*)((const u16*)x + (size_t)n * 256 + o);
        }
        *(bf8*)(xc + (size_t)n * 768 + 512 + o) = v;
    } else if (idx < PR_D0) {                            // conv weight transpose
        int i = idx - PR_C0;
        int kk = i & 63;
        int n = (i >> 6) & 255;
        int lc = i >> 14;            // l*36 + ck
        int l = lc / 36, ck = lc % 36;
        int k = ck * 64 + kk;
        u16 v;
        if (k < 2048) {
            int r = k >> 8, ii = k & 255;
            v = load_cvt(conv_W, ((size_t)((l * 8 + r) * 256 + ii)) * 256 + n, f32);
        } else {
            int ii = k - 2048;
            v = load_cvt(conv_root, ((size_t)(l * 256 + ii)) * 256 + n, f32);
        }
        Wt[i] = v;
    } else if (idx < PR_END) {                           // W_hh pack
        int i = idx - PR_D0;
        int c = i & 3, j = (i >> 2) & 1023, i4 = i >> 12;
        int i2 = i4 * 4 + c;
        float a, b;
        if (f32) {
            a = ((const float*)W_hh)[j * 256 + 2 * i2];
            b = ((const float*)W_hh)[j * 256 + 2 * i2 + 1];
        } else {
            a = b2f(((const u16*)W_hh)[j * 256 + 2 * i2]);
            b = b2f(((const u16*)W_hh)[j * 256 + 2 * i2 + 1]);
        }
        whh4[i] = packh2(a, b);
    }
}

// ---------------- dense per-relation transform over a node chunk ----------------
__launch_bounds__(256, 3)
__global__ void k_layer2(const u16* __restrict__ xprev,      // stride 768
                         const u16* __restrict__ WtL,        // [36][256][64]
                         u16* __restrict__ Hall, int n0, int chnc) {
    __shared__ u16 As[64 * 264];
    int m0 = n0 + blockIdx.x * 64;
    int rg = blockIdx.y;
    int nend = n0 + chnc;
    int wave = threadIdx.x >> 6, lane = threadIdx.x & 63;
    int mrow = lane & 15, quad = lane >> 4;
    int nbase = wave * 64;

    // stage A tile [64][256] (dense, coalesced; zero-pad past chunk)
    {
        int row = threadIdx.x >> 2, sg = threadIdx.x & 3;
        int gm = m0 + row;
        u16* dstp = As + row * 264 + sg * 64;
        if (gm < nend) {
            const u16* srcp = xprev + (size_t)gm * 768 + sg * 64;
            #pragma unroll
            for (int c = 0; c < 8; ++c)
                *(bf8*)(dstp + c * 8) = *(const bf8*)(srcp + c * 8);
        } else {
            bf8 z = {0, 0, 0, 0, 0, 0, 0, 0};
            #pragma unroll
            for (int c = 0; c < 8; ++c) *(bf8*)(dstp + c * 8) = z;
        }
    }
    __syncthreads();

    f4 acc[4][4];
    #pragma unroll
    for (int nt = 0; nt < 4; ++nt)
        #pragma unroll
        for (int mh = 0; mh < 4; ++mh) acc[nt][mh] = (f4){0.0f, 0.0f, 0.0f, 0.0f};

    const u16* WtR = WtL + (size_t)(rg * 4) * 16384;   // ck = rg*4 + c4 (rg==8 -> root)
    #pragma unroll
    for (int c4 = 0; c4 < 4; ++c4) {
        const u16* Bck = WtR + (size_t)c4 * 16384;
        #pragma unroll
        for (int ks = 0; ks < 2; ++ks) {
            bf8 a[4];
            #pragma unroll
            for (int mh = 0; mh < 4; ++mh)
                a[mh] = *(const bf8*)(As + (mh * 16 + mrow) * 264 + c4 * 64 + ks * 32 + quad * 8);
            #pragma unroll
            for (int nt = 0; nt < 4; ++nt) {
                bf8 b = *(const bf8*)(Bck + (size_t)(nbase + nt * 16 + mrow) * 64
                                      + ks * 32 + quad * 8);
                #pragma unroll
                for (int mh = 0; mh < 4; ++mh)
                    acc[nt][mh] = __builtin_amdgcn_mfma_f32_16x16x32_bf16(a[mh], b, acc[nt][mh], 0, 0, 0);
            }
        }
    }

    // epilogue: restage to LDS ([64 m][256 n] stride 264), coalesced b128 store
    __syncthreads();
    #pragma unroll
    for (int nt = 0; nt < 4; ++nt) {
        int col = nbase + nt * 16 + mrow;
        #pragma unroll
        for (int mh = 0; mh < 4; ++mh)
            #pragma unroll
            for (int v = 0; v < 4; ++v)
                As[(mh * 16 + quad * 4 + v) * 264 + col] = f2b(acc[nt][mh][v]);
    }
    __syncthreads();
    {
        int row = threadIdx.x >> 2, sg = threadIdx.x & 3;
        int gm = m0 + row;
        if (gm < nend) {
            u16* dst = Hall + ((size_t)rg * chnc + (gm - n0)) * 256 + sg * 64;
            const u16* srcp = As + row * 264 + sg * 64;
            #pragma unroll
            for (int c = 0; c < 8; ++c)
                *(bf8*)(dst + c * 8) = *(const bf8*)(srcp + c * 8);
        }
    }
}

// ---------------- edge gather over transformed features ----------------
__launch_bounds__(256)
__global__ void k_gather(const unsigned int* __restrict__ seg,
                         const unsigned int* __restrict__ skey,
                         const float* __restrict__ sw,
                         const u16* __restrict__ Hall,
                         const u16* __restrict__ bias,
                         u16* __restrict__ xc, int colbase, int n0, int chnc) {
    int nl = blockIdx.x * 4 + (threadIdx.x >> 6);
    if (nl >= chnc) return;
    int n = n0 + nl;
    int lane = threadIdx.x & 63;
    int c0 = lane * 4;
    unsigned e0 = seg[n * 8], e1 = seg[n * 8 + 8];
    float a0 = 0.0f, a1 = 0.0f, a2 = 0.0f, a3 = 0.0f;
    unsigned key = 0; float w = 0.0f;
    if (e0 < e1) { key = skey[e0]; w = sw[e0]; }
    for (unsigned e = e0; e < e1;) {
        unsigned kc = key; float wc = w;
        ++e;
        if (e < e1) { key = skey[e]; w = sw[e]; }   // prefetch next key while row load flies
        const u16* row = Hall + ((size_t)(kc >> 16) * chnc + (kc & 0xFFFFu)) * 256 + c0;
        bf4 v = *(const bf4*)row;
        a0 += wc * b2f((u16)v[0]);
        a1 += wc * b2f((u16)v[1]);
        a2 += wc * b2f((u16)v[2]);
        a3 += wc * b2f((u16)v[3]);
    }
    const u16* rr = Hall + ((size_t)8 * chnc + nl) * 256 + c0;
    bf4 rv = *(const bf4*)rr;
    float o0 = a0 + b2f((u16)rv[0]) + b2f(bias[c0 + 0]);
    float o1 = a1 + b2f((u16)rv[1]) + b2f(bias[c0 + 1]);
    float o2 = a2 + b2f((u16)rv[2]) + b2f(bias[c0 + 2]);
    float o3 = a3 + b2f((u16)rv[3]) + b2f(bias[c0 + 3]);
    bf4 o;
    o[0] = (short)f2b(o0 > 0.0f ? o0 : 0.0f);
    o[1] = (short)f2b(o1 > 0.0f ? o1 : 0.0f);
    o[2] = (short)f2b(o2 > 0.0f ? o2 : 0.0f);
    o[3] = (short)f2b(o3 > 0.0f ? o3 : 0.0f);
    *(bf4*)(xc + (size_t)n * 768 + colbase + c0) = o;
}

// ---------------- pool scorer: one wave per node, all 9 dots fused ----------------
__launch_bounds__(256)
__global__ void k_pool(const u16* __restrict__ xc, const u16* __restrict__ parms,
                       float* __restrict__ p, float* __restrict__ score) {
    int n = blockIdx.x * 4 + (threadIdx.x >> 6);
    if (n >= N_NODES) return;
    int lane = threadIdx.x & 63;
    const u16* xr = xc + (size_t)n * 768;
    float acc[9];
    #pragma unroll
    for (int rr = 0; rr < 9; ++rr) acc[rr] = 0.0f;
    #pragma unroll
    for (int q = 0; q < 12; ++q) {
        int f = lane + 64 * q;
        float xv = b2f(xr[f]);
        #pragma unroll
        for (int rr = 0; rr < 8; ++rr)
            acc[rr] += xv * b2f(parms[P_POOL_W + rr * 768 + f]);
        acc[8] += xv * b2f(parms[P_POOL_ROOT + f]);
    }
    #pragma unroll
    for (int rr = 0; rr < 9; ++rr) acc[rr] = wred(acc[rr]);
    if (lane == 0) {
        #pragma unroll
        for (int rr = 0; rr < 8; ++rr) p[rr * N_NODES + n] = acc[rr];
        score[n] = acc[8] + b2f(parms[P_POOL_BIAS]);
    }
}
__global__ void k_scatter_pool(const int* __restrict__ src, const int* __restrict__ dst,
                               const int* __restrict__ et, const unsigned int* __restrict__ cnt,
                               const float* __restrict__ p, float* __restrict__ score) {
    int e = blockIdx.x * 256 + threadIdx.x;
    if (e >= N_EDGES) return;
    int r = et[e] & 7;
    unsigned s = (unsigned)src[e]; if (s >= N_NODES) s = 0;
    unsigned d = (unsigned)dst[e]; if (d >= N_NODES) d = 0;
    unsigned c = cnt[d * 8 + r];
    float iv = 1.0f / (float)(c < 1u ? 1u : c);
    atomicAdd(&score[d], iv * p[r * N_NODES + s]);
}

// ---------------- per-graph top-K sort ----------------
__launch_bounds__(256)
__global__ void k_sort(const float* __restrict__ score, unsigned int* __restrict__ topidx,
                       float* __restrict__ topv) {
    __shared__ unsigned long long keys[512];
    __shared__ float vals[512];
    int g = blockIdx.x, tid = threadIdx.x;
    for (int i = tid; i < 512; i += 256) {
        unsigned long long key;
        float v = 0.0f;
        if (i < NPG) {
            v = tanhf(score[g * NPG + i]);
            unsigned int u = __float_as_uint(v);
            u = (u & 0x80000000u) ? ~u : (u | 0x80000000u);
            u = ~u;
            key = ((unsigned long long)u << 32) | (unsigned int)i;
        } else {
            key = 0xFFFFFFFFFFFFFFFFull;
        }
        keys[i] = key;
        vals[i] = v;
    }
    __syncthreads();
    for (int k = 2; k <= 512; k <<= 1)
        for (int j = k >> 1; j > 0; j >>= 1) {
            for (int i = tid; i < 512; i += 256) {
                int ixj = i ^ j;
                if (ixj > i) {
                    bool up = ((i & k) == 0);
                    unsigned long long a = keys[i], b = keys[ixj];
                    if ((a > b) == up) { keys[i] = b; keys[ixj] = a; }
                }
            }
            __syncthreads();
        }
    if (tid < KTOP) {
        int idx = (int)(keys[tid] & 511u);
        topidx[g * 256 + tid] = (unsigned)idx;
        topv[g * 256 + tid] = vals[idx];
    }
}

// ---------------- parallel weighted readout ----------------
__launch_bounds__(256)
__global__ void k_readout(const unsigned int* __restrict__ topidx,
                          const float* __restrict__ topv,
                          const u16* __restrict__ xc, float* __restrict__ readout) {
    __shared__ unsigned int sidx[KTOP];
    __shared__ float sv[KTOP];
    __shared__ float part[256];
    int g = blockIdx.x, cb = blockIdx.y;
    int tid = threadIdx.x;
    if (tid < KTOP) { sidx[tid] = topidx[g * 256 + tid]; sv[tid] = topv[g * 256 + tid]; }
    __syncthreads();
    int fl = tid & 63, ng = tid >> 6;
    int f = cb * 64 + fl;
    float acc = 0.0f;
    for (int j = ng; j < KTOP; j += 4)
        acc += sv[j] * b2f(xc[(size_t)(g * NPG + sidx[j]) * 768 + f]);
    part[tid] = acc;
    __syncthreads();
    if (tid < 64) {
        float s = part[tid] + part[64 + tid] + part[128 + tid] + part[192 + tid];
        readout[(size_t)g * 768 + cb * 64 + tid] = s * (1.0f / (float)KTOP);
    }
}

// ---------------- fc1 + LSTM input precompute ----------------
__global__ void k_fc1(const float* __restrict__ readout, const u16* __restrict__ parms,
                      float* __restrict__ h1) {
    int wid = blockIdx.x * 4 + (threadIdx.x >> 6);
    if (wid >= NGRAPH * 256) return;
    int g = wid >> 8, o = wid & 255, lane = threadIdx.x & 63;
    const float* rr = readout + (size_t)g * 768;
    const u16* w = parms + P_FC1_W + (size_t)o * 768;
    float s = 0.0f;
    #pragma unroll
    for (int q = 0; q < 12; ++q) { int f = lane + 64 * q; s += rr[f] * b2f(w[f]); }
    s = wred(s);
    if (lane == 0) { s += b2f(parms[P_FC1_B + o]); h1[g * 256 + o] = s > 0.0f ? s : 0.0f; }
}
__global__ void k_gx(const float* __restrict__ h1, const u16* __restrict__ parms,
                     float* __restrict__ gx) {
    int wid = blockIdx.x * 4 + (threadIdx.x >> 6);
    if (wid >= NGRAPH * 1024) return;
    int t = wid >> 10, j = wid & 1023, lane = threadIdx.x & 63;
    const float* xr = h1 + t * 256;
    const u16* w = parms + P_W_IH + (size_t)j * 256;
    float s = 0.0f;
    #pragma unroll
    for (int q = 0; q < 4; ++q) { int f = lane + 64 * q; s += xr[f] * b2f(w[f]); }
    s = wred(s);
    if (lane == 0) gx[t * 1024 + j] = s + b2f(parms[P_B_IH + j]) + b2f(parms[P_B_HH + j]);
}

// ---------------- sequential LSTM (round-3 variant, proven 107 us) ----------
// 5 attempts to beat this (reg/LDS/AGPR pinning, 2x multi-CU) all failed:
// the RA spills the 192 weight regs no matter what; single-CU L2 streaming of
// 512 KB/step (~80 B/cyc) is the floor; cross-XCD sync costs ~3.5 us/step.
__launch_bounds__(512, 1)
__global__ void k_lstm(const float* __restrict__ gx, const unsigned int* __restrict__ whh4,
                       const u16* __restrict__ parms, void* __restrict__ out,
                       const unsigned int* __restrict__ flag) {
    __shared__ float hs[256];
    __shared__ unsigned int hs2[128];
    __shared__ float gs[1024];
    __shared__ float red[2];
    int tid = threadIdx.x;
    int j0 = tid, j1 = tid + 512;
    u4v wa[24], wb[24];
    #pragma unroll
    for (int q = 0; q < 24; ++q) {
        wa[q] = *(const u4v*)(whh4 + (((size_t)q * 1024) + j0) * 4);
        wb[q] = *(const u4v*)(whh4 + (((size_t)q * 1024) + j1) * 4);
    }
    asm volatile("" : "+v"(wa[0]), "+v"(wa[1]), "+v"(wa[2]), "+v"(wa[3]),
                      "+v"(wa[4]), "+v"(wa[5]), "+v"(wa[6]), "+v"(wa[7]),
                      "+v"(wa[8]), "+v"(wa[9]), "+v"(wa[10]), "+v"(wa[11]),
                      "+v"(wa[12]), "+v"(wa[13]), "+v"(wa[14]), "+v"(wa[15]),
                      "+v"(wa[16]), "+v"(wa[17]), "+v"(wa[18]), "+v"(wa[19]),
                      "+v"(wa[20]), "+v"(wa[21]), "+v"(wa[22]), "+v"(wa[23]));
    asm volatile("" : "+v"(wb[0]), "+v"(wb[1]), "+v"(wb[2]), "+v"(wb[3]),
                      "+v"(wb[4]), "+v"(wb[5]), "+v"(wb[6]), "+v"(wb[7]),
                      "+v"(wb[8]), "+v"(wb[9]), "+v"(wb[10]), "+v"(wb[11]),
                      "+v"(wb[12]), "+v"(wb[13]), "+v"(wb[14]), "+v"(wb[15]),
                      "+v"(wb[16]), "+v"(wb[17]), "+v"(wb[18]), "+v"(wb[19]),
                      "+v"(wb[20]), "+v"(wb[21]), "+v"(wb[22]), "+v"(wb[23]));
    if (tid < 256) hs[tid] = 0.0f;
    if (tid < 128) hs2[tid] = 0u;
    float c = 0.0f;
    __syncthreads();
    for (int t = 0; t < NGRAPH; ++t) {
        float g0 = gx[t * 1024 + j0];
        float g1 = gx[t * 1024 + j1];
        #pragma unroll
        for (int q = 0; q < 24; ++q) {
            #pragma unroll
            for (int cc = 0; cc < 4; ++cc) {
                unsigned h2 = hs2[q * 4 + cc];
                g0 = fdot2u(wa[q][cc], h2, g0);
                g1 = fdot2u(wb[q][cc], h2, g1);
            }
        }
        #pragma unroll 2
        for (int q = 24; q < 32; ++q) {
            u4v v0 = *(const u4v*)(whh4 + (((size_t)q * 1024) + j0) * 4);
            u4v v1 = *(const u4v*)(whh4 + (((size_t)q * 1024) + j1) * 4);
            #pragma unroll
            for (int cc = 0; cc < 4; ++cc) {
                unsigned h2 = hs2[q * 4 + cc];
                g0 = fdot2u(v0[cc], h2, g0);
                g1 = fdot2u(v1[cc], h2, g1);
            }
        }
        gs[j0] = g0;
        gs[j1] = g1;
        __syncthreads();
        if (tid < 256) {
            float gi = sigm_f(gs[tid]);
            float gf = sigm_f(gs[256 + tid]);
            float gg = tanh_f(gs[512 + tid]);
            float go = sigm_f(gs[768 + tid]);
            c = gf * c + gi * gg;
            float h = go * tanh_f(c);
            hs[tid] = h;
            float ho = __shfl(h, (tid & 63) ^ 1);
            if (!(tid & 1)) hs2[tid >> 1] = packh2(h, ho);
        }
        __syncthreads();
    }
    if (tid < 128) {
        int cls = tid >> 6, lane = tid & 63;
        float s = 0.0f;
        #pragma unroll
        for (int q = 0; q < 4; ++q) {
            int d = lane + 64 * q;
            s += hs[d] * b2f(parms[P_FC2_W + cls * 256 + d]);
        }
        s = wred(s);
        if (lane == 0) red[cls] = s + b2f(parms[P_FC2_B + cls]);
    }
    __syncthreads();
    if (tid == 0) {
        float l0 = red[0], l1 = red[1];
        float m = fmaxf(l0, l1);
        float lse = m + logf(expf(l0 - m) + expf(l1 - m));
        float o0 = l0 - lse, o1 = l1 - lse;
        if (*flag) { ((float*)out)[0] = o0; ((float*)out)[1] = o1; }
        else       { ((u16*)out)[0] = f2b(o0); ((u16*)out)[1] = f2b(o1); }
    }
}

// ---------------- workspace plan (Hall sized by chunk cap) ----------------
struct WS {
    unsigned int* flag; unsigned int* cnt; unsigned int* seg; unsigned int* ctr;
    unsigned int* skey; float* sw; unsigned int* bsum;
    u16* Wt2; u16* xc; u16* Hall; float* p; float* score;
    unsigned int* topidx; float* topv; float* readout; float* h1;
    float* gx; unsigned int* whh4; u16* parms;
    size_t need;
};
static WS plan(char* base, int cap) {
    WS w; size_t off = 0;
    auto take = [&](size_t bytes) -> char* {
        char* p = base + off; off += (bytes + 255) & ~(size_t)255; return p;
    };
    w.flag    = (unsigned int*)take(256);
    w.cnt     = (unsigned int*)take((size_t)NSEG * 4);
    w.seg     = (unsigned int*)take((size_t)(NSEG + 1) * 4);
    w.ctr     = (unsigned int*)take((size_t)NSEG * 4);
    w.skey    = (unsigned int*)take((size_t)N_EDGES * 4);
    w.sw      = (float*)take((size_t)N_EDGES * 4);
    w.bsum    = (unsigned int*)take(1024 * 4);
    w.Wt2     = (u16*)take((size_t)3 * 36 * 256 * 64 * 2);
    w.xc      = (u16*)take((size_t)N_NODES * 768 * 2);
    w.Hall    = (u16*)take((size_t)9 * cap * 256 * 2);
    w.p       = (float*)take((size_t)8 * N_NODES * 4);
    w.score   = (float*)take((size_t)N_NODES * 4);
    w.topidx  = (unsigned int*)take((size_t)NGRAPH * 256 * 4);
    w.topv    = (float*)take((size_t)NGRAPH * 256 * 4);
    w.readout = (float*)take((size_t)NGRAPH * 768 * 4);
    w.h1      = (float*)take((size_t)NGRAPH * 256 * 4);
    w.gx      = (float*)take((size_t)NGRAPH * 1024 * 4);
    w.whh4    = (unsigned int*)take((size_t)32 * 1024 * 4 * 4);
    w.parms   = (u16*)take((size_t)P_TOTAL * 2);
    w.need = off;
    return w;
}

extern "C" void kernel_launch(void* const* d_in, const int* in_sizes, int n_in,
                              void* d_out, int out_size, void* d_ws, size_t ws_size,
                              hipStream_t stream) {
    (void)in_sizes; (void)n_in; (void)out_size;
    const void* x        = d_in[0];
    const int* edge_index= (const int*)d_in[1];
    const int* edge_attr = (const int*)d_in[2];
    const void* conv_W   = d_in[4];
    const void* conv_root= d_in[5];
    const void* conv_bias= d_in[6];
    const void* pool_W   = d_in[7];
    const void* pool_root= d_in[8];
    const void* pool_bias= d_in[9];
    const void* fc1_W    = d_in[10];
    const void* fc1_b    = d_in[11];
    const void* W_ih     = d_in[12];
    const void* W_hh     = d_in[13];
    const void* b_ih     = d_in[14];
    const void* b_hh     = d_in[15];
    const void* fc2_W    = d_in[16];
    const void* fc2_b    = d_in[17];

    const int* e_src = edge_index;
    const int* e_dst = edge_index + N_EDGES;

    // chunk cap (multiple of NPG so chunks are whole graphs); unequal last chunk ok
    if (ws_size == 0) ws_size = (size_t)64 << 20;
    int cap = 500;
    {
        const int ladder[9] = {20000, 10000, 7000, 5000, 4000, 2500, 2000, 1000, 500};
        for (int i = 0; i < 9; ++i) {
            if (plan((char*)d_ws, ladder[i]).need <= ws_size) { cap = ladder[i]; break; }
        }
    }
    WS w = plan((char*)d_ws, cap);

    k_init<<<(NSEG + 255) / 256, 256, 0, stream>>>(w.flag, w.cnt, w.ctr);
    k_detect1<<<64, 256, 0, stream>>>((const u16*)x, 1 << 18, w.flag);
    k_count<<<1250, 256, 0, stream>>>(e_dst, edge_attr, w.cnt, w.flag);
    k_scan1<<<625, 256, 0, stream>>>(w.cnt, w.seg, w.bsum);
    k_scan2<<<1, 1024, 0, stream>>>(w.bsum, 625);
    k_scan3<<<(NSEG + 255) / 256, 256, 0, stream>>>(w.seg, w.bsum);
    k_place<<<1250, 256, 0, stream>>>(e_src, e_dst, edge_attr, w.seg, w.ctr, w.cnt,
                                      w.skey, w.sw, cap);

    k_prep<<<(PR_END + 255) / 256, 256, 0, stream>>>(
        conv_bias, pool_W, pool_root, pool_bias, fc1_W, fc1_b,
        W_ih, b_ih, b_hh, fc2_W, fc2_b,
        x, conv_W, conv_root, W_hh,
        w.parms, w.xc, w.Wt2, w.whh4, w.flag);

    for (int l = 0; l < 3; ++l) {
        const u16* xprev = w.xc + (l == 0 ? 512 : (l - 1) * 256);
        const u16* WtL = w.Wt2 + (size_t)l * 36 * 16384;
        const u16* bias = w.parms + P_CONV_BIAS + l * 256;
        for (int n0 = 0; n0 < N_NODES; n0 += cap) {
            int chnc = N_NODES - n0 < cap ? N_NODES - n0 : cap;
            int tiles = (chnc + 63) / 64;
            k_layer2<<<dim3(tiles, 9), 256, 0, stream>>>(xprev, WtL, w.Hall, n0, chnc);
            k_gather<<<(chnc + 3) / 4, 256, 0, stream>>>(w.seg, w.skey, w.sw, w.Hall,
                                                         bias, w.xc, l * 256, n0, chnc);
        }
    }

    k_pool<<<5000, 256, 0, stream>>>(w.xc, w.parms, w.p, w.score);
    k_scatter_pool<<<1250, 256, 0, stream>>>(e_src, e_dst, edge_attr, w.cnt, w.p, w.score);
    k_sort<<<NGRAPH, 256, 0, stream>>>(w.score, w.topidx, w.topv);
    k_readout<<<dim3(NGRAPH, 12), 256, 0, stream>>>(w.topidx, w.topv, w.xc, w.readout);
    k_fc1<<<2560, 256, 0, stream>>>(w.readout, w.parms, w.h1);
    k_gx<<<10240, 256, 0, stream>>>(w.h1, w.parms, w.gx);
    k_lstm<<<1, 512, 0, stream>>>(w.gx, w.whh4, w.parms, d_out, w.flag);
}

// Round 11
// 682.834 us; speedup vs baseline: 1.5570x; 1.0059x over previous
//
#include <hip/hip_runtime.h>

typedef unsigned short u16;
typedef short bf8 __attribute__((ext_vector_type(8)));
typedef short bf4 __attribute__((ext_vector_type(4)));
typedef float f4 __attribute__((ext_vector_type(4)));
typedef _Float16 h2v __attribute__((ext_vector_type(2)));
typedef __fp16 g2v __attribute__((ext_vector_type(2)));
typedef unsigned int u4v __attribute__((ext_vector_type(4)));

#define N_NODES 20000
#define N_EDGES 320000
#define NGRAPH 40
#define NPG 500
#define KTOP 250
#define NSEG (N_NODES * 8)

// parms arena offsets (u16 elements)
#define P_CONV_BIAS 0
#define P_POOL_W    768
#define P_POOL_ROOT 6912
#define P_POOL_BIAS 7680
#define P_FC1_W     7688
#define P_FC1_B     204296
#define P_W_IH      204552
#define P_B_IH      466696
#define P_B_HH      467720
#define P_FC2_W     468744
#define P_FC2_B     469256
#define P_TOTAL     469264

// k_prep range boundaries (flat thread index)
#define PR_B0 469264                      // + P_TOTAL
#define PR_C0 (PR_B0 + 640000)            // + N_NODES*32 stage-x octets
#define PR_D0 (PR_C0 + 1769472)           // + 3*36*256*64 transpose elems
#define PR_END (PR_D0 + 131072)           // + 32*1024*4 whh4 elems

__device__ __forceinline__ float b2f(u16 u) {
    union { unsigned int i; float f; } v; v.i = ((unsigned int)u) << 16; return v.f;
}
__device__ __forceinline__ u16 f2b(float f) {
    union { float f; unsigned int i; } v; v.f = f;
    unsigned int x = v.i;
    return (u16)((x + 0x7fffu + ((x >> 16) & 1u)) >> 16);
}
__device__ __forceinline__ float wred(float s) {
    #pragma unroll
    for (int off = 32; off > 0; off >>= 1) s += __shfl_down(s, off);
    return s;
}
__device__ __forceinline__ float fdot2u(unsigned a, unsigned b, float c) {
#if __has_builtin(__builtin_amdgcn_fdot2)
    union { unsigned u; h2v h; } ua, ub; ua.u = a; ub.u = b;
    return __builtin_amdgcn_fdot2(ua.h, ub.h, c, false);
#else
    union { unsigned u; g2v h; } ua, ub; ua.u = a; ub.u = b;
    return c + (float)ua.h[0] * (float)ub.h[0] + (float)ua.h[1] * (float)ub.h[1];
#endif
}
__device__ __forceinline__ unsigned packh2(float a, float b) {
    g2v h = __builtin_amdgcn_cvt_pkrtz(a, b);
    union { g2v h; unsigned u; } v; v.h = h; return v.u;
}
// fast activations (v_exp based); |err| ~1e-6, far under output tolerance
__device__ __forceinline__ float sigm_f(float x) {
    return 1.0f / (1.0f + __expf(-x));
}
__device__ __forceinline__ float tanh_f(float x) {
    return 1.0f - 2.0f / (1.0f + __expf(2.0f * x));
}

// ---------------- init: zero flag + cnt + ctr ----------------
__global__ void k_init(unsigned int* __restrict__ flag, unsigned int* __restrict__ cnt,
                       unsigned int* __restrict__ ctr) {
    int i = blockIdx.x * 256 + threadIdx.x;
    if (i < 64) flag[i] = 0u;
    if (i < NSEG) { cnt[i] = 0u; ctr[i] = 0u; }
}

// ---------------- dtype detection (parallel) ----------------
__global__ void k_detect1(const u16* __restrict__ xr, int n, unsigned int* __restrict__ fb) {
    unsigned int local = 0;
    for (int i = blockIdx.x * 256 + threadIdx.x; i < n; i += 64 * 256) {
        unsigned int u = xr[i];
        if (((u >> 7) & 0xFFu) == 0xFFu) local++;
    }
    local = (unsigned int)wred((float)local);
    if ((threadIdx.x & 63) == 0 && local) atomicAdd(&fb[1], local);
}

__device__ __forceinline__ u16 load_cvt(const void* src, size_t i, bool f32) {
    return f32 ? f2b(((const float*)src)[i]) : ((const u16*)src)[i];
}

// ---------------- degree counts (+ flag finalize) ----------------
__global__ void k_count(const int* __restrict__ dst, const int* __restrict__ et,
                        unsigned int* __restrict__ cnt, unsigned int* __restrict__ fb) {
    int e = blockIdx.x * 256 + threadIdx.x;
    if (e == 0) fb[0] = (fb[1] > 8u) ? 1u : 0u;
    if (e < N_EDGES) {
        unsigned d = (unsigned)dst[e]; if (d >= N_NODES) d = 0;
        unsigned r = (unsigned)et[e] & 7u;
        atomicAdd(&cnt[d * 8 + r], 1u);
    }
}

// ---------------- prefix scan (exclusive) over cnt[160000] ----------------
__global__ void k_scan1(const unsigned int* __restrict__ cnt, unsigned int* __restrict__ seg,
                        unsigned int* __restrict__ bsum) {
    __shared__ unsigned int s[256];
    int t = threadIdx.x, i = blockIdx.x * 256 + t;
    unsigned int v = (i < NSEG) ? cnt[i] : 0u;
    s[t] = v;
    __syncthreads();
    for (int off = 1; off < 256; off <<= 1) {
        unsigned int add = (t >= off) ? s[t - off] : 0u;
        __syncthreads();
        s[t] += add;
        __syncthreads();
    }
    if (i < NSEG) seg[i] = s[t] - v;
    if (t == 255) bsum[blockIdx.x] = s[255];
}
__global__ void k_scan2(unsigned int* __restrict__ bsum, int nb) {
    __shared__ unsigned int s[1024];
    int t = threadIdx.x;
    unsigned int v = (t < nb) ? bsum[t] : 0u;
    s[t] = v;
    __syncthreads();
    for (int off = 1; off < 1024; off <<= 1) {
        unsigned int add = (t >= off) ? s[t - off] : 0u;
        __syncthreads();
        s[t] += add;
        __syncthreads();
    }
    if (t < nb) bsum[t] = s[t] - v;
}
__global__ void k_scan3(unsigned int* __restrict__ seg, const unsigned int* __restrict__ bsum) {
    int i = blockIdx.x * 256 + threadIdx.x;
    if (i < NSEG) seg[i] += bsum[i >> 8];
    if (i == 0) seg[NSEG] = N_EDGES;
}
// place edges into (dst,rel)-sorted order; skey = chunk-local src | (rel<<16)
__global__ void k_place(const int* __restrict__ src, const int* __restrict__ dst,
                        const int* __restrict__ et, const unsigned int* __restrict__ seg,
                        unsigned int* __restrict__ ctr, const unsigned int* __restrict__ cnt,
                        unsigned int* __restrict__ skey, float* __restrict__ sw, int cap) {
    int e = blockIdx.x * 256 + threadIdx.x;
    if (e >= N_EDGES) return;
    unsigned s = (unsigned)src[e]; if (s >= N_NODES) s = 0;
    unsigned d = (unsigned)dst[e]; if (d >= N_NODES) d = 0;
    unsigned r = (unsigned)et[e] & 7u;
    unsigned key = d * 8 + r;
    unsigned pos = seg[key] + atomicAdd(&ctr[key], 1u);
    unsigned base = (d / (unsigned)cap) * (unsigned)cap;   // chunks are whole graphs
    unsigned sl = s - base;
    if (sl >= (unsigned)cap) sl = 0u;            // defensive: keep in-bounds
    skey[pos] = sl | (r << 16);
    unsigned c = cnt[key];
    sw[pos] = 1.0f / (float)(c < 1u ? 1u : c);
}

// ---------------- fused one-shot prep: cvt_all | stage_x | transpose2 | whh4 -----
__global__ void k_prep(const void* conv_bias, const void* pool_W, const void* pool_root,
                       const void* pool_bias, const void* fc1_W, const void* fc1_b,
                       const void* W_ih, const void* b_ih, const void* b_hh,
                       const void* fc2_W, const void* fc2_b,
                       const void* __restrict__ x, const void* __restrict__ conv_W,
                       const void* __restrict__ conv_root, const void* __restrict__ W_hh,
                       u16* __restrict__ parms, u16* __restrict__ xc,
                       u16* __restrict__ Wt, unsigned int* __restrict__ whh4,
                       const unsigned int* __restrict__ flag) {
    int idx = blockIdx.x * 256 + threadIdx.x;
    bool f32 = (*flag != 0u);
    if (idx < PR_B0) {                                   // param canonicalization
        int i = idx;
        u16 v;
        if      (i < P_CONV_BIAS + 768)    v = load_cvt(conv_bias, i - P_CONV_BIAS, f32);
        else if (i < P_POOL_W + 6144)      v = load_cvt(pool_W,    i - P_POOL_W, f32);
        else if (i < P_POOL_ROOT + 768)    v = load_cvt(pool_root, i - P_POOL_ROOT, f32);
        else if (i < P_POOL_BIAS + 1)      v = load_cvt(pool_bias, i - P_POOL_BIAS, f32);
        else if (i < P_FC1_W && i >= P_POOL_BIAS) return;   // alignment gap
        else if (i < P_FC1_W + 196608)     v = load_cvt(fc1_W,    i - P_FC1_W, f32);
        else if (i < P_FC1_B + 256)        v = load_cvt(fc1_b,    i - P_FC1_B, f32);
        else if (i < P_W_IH + 262144)      v = load_cvt(W_ih,     i - P_W_IH, f32);
        else if (i < P_B_IH + 1024)        v = load_cvt(b_ih,     i - P_B_IH, f32);
        else if (i < P_B_HH + 1024)        v = load_cvt(b_hh,     i - P_B_HH, f32);
        else if (i < P_FC2_W + 512)        v = load_cvt(fc2_W,    i - P_FC2_W, f32);
        else if (i < P_FC2_B + 2)          v = load_cvt(fc2_b,    i - P_FC2_B, f32);
        else return;
        parms[i] = v;
    } else if (idx < PR_C0) {                            // stage x -> xc[:,512:768]
        int i = idx - PR_B0;
        int n = i >> 5, o = (i & 31) * 8;
        bf8 v;
        if (f32) {
            const float* s = (const float*)x + (size_t)n * 256 + o;
            #pragma unroll
            for (int c = 0; c < 8; ++c) v[c] = (short)f2b(s[c]);
        } else {
            v = *(const bf8*)((const u16*)x + (size_t)n * 256 + o);
        }
        *(bf8*)(xc + (size_t)n * 768 + 512 + o) = v;
    } else if (idx < PR_D0) {                            // conv weight transpose
        int i = idx - PR_C0;
        int kk = i & 63;
        int n = (i >> 6) & 255;
        int lc = i >> 14;            // l*36 + ck
        int l = lc / 36, ck = lc % 36;
        int k = ck * 64 + kk;
        u16 v;
        if (k < 2048) {
            int r = k >> 8, ii = k & 255;
            v = load_cvt(conv_W, ((size_t)((l * 8 + r) * 256 + ii)) * 256 + n, f32);
        } else {
            int ii = k - 2048;
            v = load_cvt(conv_root, ((size_t)(l * 256 + ii)) * 256 + n, f32);
        }
        Wt[i] = v;
    } else if (idx < PR_END) {                           // W_hh pack
        int i = idx - PR_D0;
        int c = i & 3, j = (i >> 2) & 1023, i4 = i >> 12;
        int i2 = i4 * 4 + c;
        float a, b;
        if (f32) {
            a = ((const float*)W_hh)[j * 256 + 2 * i2];
            b = ((const float*)W_hh)[j * 256 + 2 * i2 + 1];
        } else {
            a = b2f(((const u16*)W_hh)[j * 256 + 2 * i2]);
            b = b2f(((const u16*)W_hh)[j * 256 + 2 * i2 + 1]);
        }
        whh4[i] = packh2(a, b);
    }
}

// ---------------- dense per-relation transform over a node chunk ----------------
// Hall[rg][local][256] = X[n0+local] @ W_rg for rg=0..7; rg==8 (root) writes its
// pre-bias transform STRAIGHT INTO xc[:, colbase:+256] (gather reads it back and
// overwrites with the final value) — shrinks Hall to 8 slices so cap=5000 fits
// the 64 MB workspace (nch 5 -> 4, 6 fewer dispatches).
__launch_bounds__(256, 3)
__global__ void k_layer2(const u16* __restrict__ xprev,      // stride 768
                         const u16* __restrict__ WtL,        // [36][256][64]
                         u16* __restrict__ Hall,
                         u16* __restrict__ xcout, int colbase, int n0, int chnc) {
    __shared__ u16 As[64 * 264];
    int m0 = n0 + blockIdx.x * 64;
    int rg = blockIdx.y;
    int nend = n0 + chnc;
    int wave = threadIdx.x >> 6, lane = threadIdx.x & 63;
    int mrow = lane & 15, quad = lane >> 4;
    int nbase = wave * 64;

    // stage A tile [64][256] (dense, coalesced; zero-pad past chunk)
    {
        int row = threadIdx.x >> 2, sg = threadIdx.x & 3;
        int gm = m0 + row;
        u16* dstp = As + row * 264 + sg * 64;
        if (gm < nend) {
            const u16* srcp = xprev + (size_t)gm * 768 + sg * 64;
            #pragma unroll
            for (int c = 0; c < 8; ++c)
                *(bf8*)(dstp + c * 8) = *(const bf8*)(srcp + c * 8);
        } else {
            bf8 z = {0, 0, 0, 0, 0, 0, 0, 0};
            #pragma unroll
            for (int c = 0; c < 8; ++c) *(bf8*)(dstp + c * 8) = z;
        }
    }
    __syncthreads();

    f4 acc[4][4];
    #pragma unroll
    for (int nt = 0; nt < 4; ++nt)
        #pragma unroll
        for (int mh = 0; mh < 4; ++mh) acc[nt][mh] = (f4){0.0f, 0.0f, 0.0f, 0.0f};

    const u16* WtR = WtL + (size_t)(rg * 4) * 16384;   // ck = rg*4 + c4 (rg==8 -> root)
    #pragma unroll
    for (int c4 = 0; c4 < 4; ++c4) {
        const u16* Bck = WtR + (size_t)c4 * 16384;
        #pragma unroll
        for (int ks = 0; ks < 2; ++ks) {
            bf8 a[4];
            #pragma unroll
            for (int mh = 0; mh < 4; ++mh)
                a[mh] = *(const bf8*)(As + (mh * 16 + mrow) * 264 + c4 * 64 + ks * 32 + quad * 8);
            #pragma unroll
            for (int nt = 0; nt < 4; ++nt) {
                bf8 b = *(const bf8*)(Bck + (size_t)(nbase + nt * 16 + mrow) * 64
                                      + ks * 32 + quad * 8);
                #pragma unroll
                for (int mh = 0; mh < 4; ++mh)
                    acc[nt][mh] = __builtin_amdgcn_mfma_f32_16x16x32_bf16(a[mh], b, acc[nt][mh], 0, 0, 0);
            }
        }
    }

    // epilogue: restage to LDS ([64 m][256 n] stride 264), coalesced b128 store
    __syncthreads();
    #pragma unroll
    for (int nt = 0; nt < 4; ++nt) {
        int col = nbase + nt * 16 + mrow;
        #pragma unroll
        for (int mh = 0; mh < 4; ++mh)
            #pragma unroll
            for (int v = 0; v < 4; ++v)
                As[(mh * 16 + quad * 4 + v) * 264 + col] = f2b(acc[nt][mh][v]);
    }
    __syncthreads();
    {
        int row = threadIdx.x >> 2, sg = threadIdx.x & 3;
        int gm = m0 + row;
        if (gm < nend) {
            u16* dst = (rg < 8)
                ? Hall + ((size_t)rg * chnc + (gm - n0)) * 256 + sg * 64
                : xcout + (size_t)gm * 768 + colbase + sg * 64;
            const u16* srcp = As + row * 264 + sg * 64;
            #pragma unroll
            for (int c = 0; c < 8; ++c)
                *(bf8*)(dst + c * 8) = *(const bf8*)(srcp + c * 8);
        }
    }
}

// ---------------- edge gather over transformed features ----------------
// root term now read from xc (written there by layer2 rg==8), then overwritten
// in place with the final biased+relu'd value by the same thread.
__launch_bounds__(256)
__global__ void k_gather(const unsigned int* __restrict__ seg,
                         const unsigned int* __restrict__ skey,
                         const float* __restrict__ sw,
                         const u16* __restrict__ Hall,
                         const u16* __restrict__ bias,
                         u16* __restrict__ xc, int colbase, int n0, int chnc) {
    int nl = blockIdx.x * 4 + (threadIdx.x >> 6);
    if (nl >= chnc) return;
    int n = n0 + nl;
    int lane = threadIdx.x & 63;
    int c0 = lane * 4;
    unsigned e0 = seg[n * 8], e1 = seg[n * 8 + 8];
    float a0 = 0.0f, a1 = 0.0f, a2 = 0.0f, a3 = 0.0f;
    unsigned key = 0; float w = 0.0f;
    if (e0 < e1) { key = skey[e0]; w = sw[e0]; }
    for (unsigned e = e0; e < e1;) {
        unsigned kc = key; float wc = w;
        ++e;
        if (e < e1) { key = skey[e]; w = sw[e]; }   // prefetch next key while row load flies
        const u16* row = Hall + ((size_t)(kc >> 16) * chnc + (kc & 0xFFFFu)) * 256 + c0;
        bf4 v = *(const bf4*)row;
        a0 += wc * b2f((u16)v[0]);
        a1 += wc * b2f((u16)v[1]);
        a2 += wc * b2f((u16)v[2]);
        a3 += wc * b2f((u16)v[3]);
    }
    u16* xrow = xc + (size_t)n * 768 + colbase + c0;
    bf4 rv = *(const bf4*)xrow;                      // root transform (pre-bias)
    float o0 = a0 + b2f((u16)rv[0]) + b2f(bias[c0 + 0]);
    float o1 = a1 + b2f((u16)rv[1]) + b2f(bias[c0 + 1]);
    float o2 = a2 + b2f((u16)rv[2]) + b2f(bias[c0 + 2]);
    float o3 = a3 + b2f((u16)rv[3]) + b2f(bias[c0 + 3]);
    bf4 o;
    o[0] = (short)f2b(o0 > 0.0f ? o0 : 0.0f);
    o[1] = (short)f2b(o1 > 0.0f ? o1 : 0.0f);
    o[2] = (short)f2b(o2 > 0.0f ? o2 : 0.0f);
    o[3] = (short)f2b(o3 > 0.0f ? o3 : 0.0f);
    *(bf4*)xrow = o;
}

// ---------------- pool scorer: one wave per node, all 9 dots fused ----------------
__launch_bounds__(256)
__global__ void k_pool(const u16* __restrict__ xc, const u16* __restrict__ parms,
                       float* __restrict__ p, float* __restrict__ score) {
    int n = blockIdx.x * 4 + (threadIdx.x >> 6);
    if (n >= N_NODES) return;
    int lane = threadIdx.x & 63;
    const u16* xr = xc + (size_t)n * 768;
    float acc[9];
    #pragma unroll
    for (int rr = 0; rr < 9; ++rr) acc[rr] = 0.0f;
    #pragma unroll
    for (int q = 0; q < 12; ++q) {
        int f = lane + 64 * q;
        float xv = b2f(xr[f]);
        #pragma unroll
        for (int rr = 0; rr < 8; ++rr)
            acc[rr] += xv * b2f(parms[P_POOL_W + rr * 768 + f]);
        acc[8] += xv * b2f(parms[P_POOL_ROOT + f]);
    }
    #pragma unroll
    for (int rr = 0; rr < 9; ++rr) acc[rr] = wred(acc[rr]);
    if (lane == 0) {
        #pragma unroll
        for (int rr = 0; rr < 8; ++rr) p[rr * N_NODES + n] = acc[rr];
        score[n] = acc[8] + b2f(parms[P_POOL_BIAS]);
    }
}
__global__ void k_scatter_pool(const int* __restrict__ src, const int* __restrict__ dst,
                               const int* __restrict__ et, const unsigned int* __restrict__ cnt,
                               const float* __restrict__ p, float* __restrict__ score) {
    int e = blockIdx.x * 256 + threadIdx.x;
    if (e >= N_EDGES) return;
    int r = et[e] & 7;
    unsigned s = (unsigned)src[e]; if (s >= N_NODES) s = 0;
    unsigned d = (unsigned)dst[e]; if (d >= N_NODES) d = 0;
    unsigned c = cnt[d * 8 + r];
    float iv = 1.0f / (float)(c < 1u ? 1u : c);
    atomicAdd(&score[d], iv * p[r * N_NODES + s]);
}

// ---------------- per-graph top-K sort ----------------
__launch_bounds__(256)
__global__ void k_sort(const float* __restrict__ score, unsigned int* __restrict__ topidx,
                       float* __restrict__ topv) {
    __shared__ unsigned long long keys[512];
    __shared__ float vals[512];
    int g = blockIdx.x, tid = threadIdx.x;
    for (int i = tid; i < 512; i += 256) {
        unsigned long long key;
        float v = 0.0f;
        if (i < NPG) {
            v = tanhf(score[g * NPG + i]);
            unsigned int u = __float_as_uint(v);
            u = (u & 0x80000000u) ? ~u : (u | 0x80000000u);
            u = ~u;
            key = ((unsigned long long)u << 32) | (unsigned int)i;
        } else {
            key = 0xFFFFFFFFFFFFFFFFull;
        }
        keys[i] = key;
        vals[i] = v;
    }
    __syncthreads();
    for (int k = 2; k <= 512; k <<= 1)
        for (int j = k >> 1; j > 0; j >>= 1) {
            for (int i = tid; i < 512; i += 256) {
                int ixj = i ^ j;
                if (ixj > i) {
                    bool up = ((i & k) == 0);
                    unsigned long long a = keys[i], b = keys[ixj];
                    if ((a > b) == up) { keys[i] = b; keys[ixj] = a; }
                }
            }
            __syncthreads();
        }
    if (tid < KTOP) {
        int idx = (int)(keys[tid] & 511u);
        topidx[g * 256 + tid] = (unsigned)idx;
        topv[g * 256 + tid] = vals[idx];
    }
}

// ---------------- parallel weighted readout ----------------
__launch_bounds__(256)
__global__ void k_readout(const unsigned int* __restrict__ topidx,
                          const float* __restrict__ topv,
                          const u16* __restrict__ xc, float* __restrict__ readout) {
    __shared__ unsigned int sidx[KTOP];
    __shared__ float sv[KTOP];
    __shared__ float part[256];
    int g = blockIdx.x, cb = blockIdx.y;
    int tid = threadIdx.x;
    if (tid < KTOP) { sidx[tid] = topidx[g * 256 + tid]; sv[tid] = topv[g * 256 + tid]; }
    __syncthreads();
    int fl = tid & 63, ng = tid >> 6;
    int f = cb * 64 + fl;
    float acc = 0.0f;
    for (int j = ng; j < KTOP; j += 4)
        acc += sv[j] * b2f(xc[(size_t)(g * NPG + sidx[j]) * 768 + f]);
    part[tid] = acc;
    __syncthreads();
    if (tid < 64) {
        float s = part[tid] + part[64 + tid] + part[128 + tid] + part[192 + tid];
        readout[(size_t)g * 768 + cb * 64 + tid] = s * (1.0f / (float)KTOP);
    }
}

// ---------------- fc1 + LSTM input precompute ----------------
__global__ void k_fc1(const float* __restrict__ readout, const u16* __restrict__ parms,
                      float* __restrict__ h1) {
    int wid = blockIdx.x * 4 + (threadIdx.x >> 6);
    if (wid >= NGRAPH * 256) return;
    int g = wid >> 8, o = wid & 255, lane = threadIdx.x & 63;
    const float* rr = readout + (size_t)g * 768;
    const u16* w = parms + P_FC1_W + (size_t)o * 768;
    float s = 0.0f;
    #pragma unroll
    for (int q = 0; q < 12; ++q) { int f = lane + 64 * q; s += rr[f] * b2f(w[f]); }
    s = wred(s);
    if (lane == 0) { s += b2f(parms[P_FC1_B + o]); h1[g * 256 + o] = s > 0.0f ? s : 0.0f; }
}
__global__ void k_gx(const float* __restrict__ h1, const u16* __restrict__ parms,
                     float* __restrict__ gx) {
    int wid = blockIdx.x * 4 + (threadIdx.x >> 6);
    if (wid >= NGRAPH * 1024) return;
    int t = wid >> 10, j = wid & 1023, lane = threadIdx.x & 63;
    const float* xr = h1 + t * 256;
    const u16* w = parms + P_W_IH + (size_t)j * 256;
    float s = 0.0f;
    #pragma unroll
    for (int q = 0; q < 4; ++q) { int f = lane + 64 * q; s += xr[f] * b2f(w[f]); }
    s = wred(s);
    if (lane == 0) gx[t * 1024 + j] = s + b2f(parms[P_B_IH + j]) + b2f(parms[P_B_HH + j]);
}

// ---------------- sequential LSTM (round-3 variant, proven 107 us) ----------
// 5 attempts to beat this (reg/LDS/AGPR pinning, 2x multi-CU) all failed:
// the RA spills the 192 weight regs no matter what; single-CU L2 streaming of
// 512 KB/step (~80 B/cyc) is the floor; cross-XCD sync costs ~3.5 us/step.
__launch_bounds__(512, 1)
__global__ void k_lstm(const float* __restrict__ gx, const unsigned int* __restrict__ whh4,
                       const u16* __restrict__ parms, void* __restrict__ out,
                       const unsigned int* __restrict__ flag) {
    __shared__ float hs[256];
    __shared__ unsigned int hs2[128];
    __shared__ float gs[1024];
    __shared__ float red[2];
    int tid = threadIdx.x;
    int j0 = tid, j1 = tid + 512;
    u4v wa[24], wb[24];
    #pragma unroll
    for (int q = 0; q < 24; ++q) {
        wa[q] = *(const u4v*)(whh4 + (((size_t)q * 1024) + j0) * 4);
        wb[q] = *(const u4v*)(whh4 + (((size_t)q * 1024) + j1) * 4);
    }
    asm volatile("" : "+v"(wa[0]), "+v"(wa[1]), "+v"(wa[2]), "+v"(wa[3]),
                      "+v"(wa[4]), "+v"(wa[5]), "+v"(wa[6]), "+v"(wa[7]),
                      "+v"(wa[8]), "+v"(wa[9]), "+v"(wa[10]), "+v"(wa[11]),
                      "+v"(wa[12]), "+v"(wa[13]), "+v"(wa[14]), "+v"(wa[15]),
                      "+v"(wa[16]), "+v"(wa[17]), "+v"(wa[18]), "+v"(wa[19]),
                      "+v"(wa[20]), "+v"(wa[21]), "+v"(wa[22]), "+v"(wa[23]));
    asm volatile("" : "+v"(wb[0]), "+v"(wb[1]), "+v"(wb[2]), "+v"(wb[3]),
                      "+v"(wb[4]), "+v"(wb[5]), "+v"(wb[6]), "+v"(wb[7]),
                      "+v"(wb[8]), "+v"(wb[9]), "+v"(wb[10]), "+v"(wb[11]),
                      "+v"(wb[12]), "+v"(wb[13]), "+v"(wb[14]), "+v"(wb[15]),
                      "+v"(wb[16]), "+v"(wb[17]), "+v"(wb[18]), "+v"(wb[19]),
                      "+v"(wb[20]), "+v"(wb[21]), "+v"(wb[22]), "+v"(wb[23]));
    if (tid < 256) hs[tid] = 0.0f;
    if (tid < 128) hs2[tid] = 0u;
    float c = 0.0f;
    __syncthreads();
    for (int t = 0; t < NGRAPH; ++t) {
        float g0 = gx[t * 1024 + j0];
        float g1 = gx[t * 1024 + j1];
        #pragma unroll
        for (int q = 0; q < 24; ++q) {
            #pragma unroll
            for (int cc = 0; cc < 4; ++cc) {
                unsigned h2 = hs2[q * 4 + cc];
                g0 = fdot2u(wa[q][cc], h2, g0);
                g1 = fdot2u(wb[q][cc], h2, g1);
            }
        }
        #pragma unroll 2
        for (int q = 24; q < 32; ++q) {
            u4v v0 = *(const u4v*)(whh4 + (((size_t)q * 1024) + j0) * 4);
            u4v v1 = *(const u4v*)(whh4 + (((size_t)q * 1024) + j1) * 4);
            #pragma unroll
            for (int cc = 0; cc < 4; ++cc) {
                unsigned h2 = hs2[q * 4 + cc];
                g0 = fdot2u(v0[cc], h2, g0);
                g1 = fdot2u(v1[cc], h2, g1);
            }
        }
        gs[j0] = g0;
        gs[j1] = g1;
        __syncthreads();
        if (tid < 256) {
            float gi = sigm_f(gs[tid]);
            float gf = sigm_f(gs[256 + tid]);
            float gg = tanh_f(gs[512 + tid]);
            float go = sigm_f(gs[768 + tid]);
            c = gf * c + gi * gg;
            float h = go * tanh_f(c);
            hs[tid] = h;
            float ho = __shfl(h, (tid & 63) ^ 1);
            if (!(tid & 1)) hs2[tid >> 1] = packh2(h, ho);
        }
        __syncthreads();
    }
    if (tid < 128) {
        int cls = tid >> 6, lane = tid & 63;
        float s = 0.0f;
        #pragma unroll
        for (int q = 0; q < 4; ++q) {
            int d = lane + 64 * q;
            s += hs[d] * b2f(parms[P_FC2_W + cls * 256 + d]);
        }
        s = wred(s);
        if (lane == 0) red[cls] = s + b2f(parms[P_FC2_B + cls]);
    }
    __syncthreads();
    if (tid == 0) {
        float l0 = red[0], l1 = red[1];
        float m = fmaxf(l0, l1);
        float lse = m + logf(expf(l0 - m) + expf(l1 - m));
        float o0 = l0 - lse, o1 = l1 - lse;
        if (*flag) { ((float*)out)[0] = o0; ((float*)out)[1] = o1; }
        else       { ((u16*)out)[0] = f2b(o0); ((u16*)out)[1] = f2b(o1); }
    }
}

// ---------------- workspace plan (Hall = 8 slices; ctr aliases p, bsum aliases score)
struct WS {
    unsigned int* flag; unsigned int* cnt; unsigned int* seg; unsigned int* ctr;
    unsigned int* skey; float* sw; unsigned int* bsum;
    u16* Wt2; u16* xc; u16* Hall; float* p; float* score;
    unsigned int* topidx; float* topv; float* readout; float* h1;
    float* gx; unsigned int* whh4; u16* parms;
    size_t need;
};
static WS plan(char* base, int cap) {
    WS w; size_t off = 0;
    auto take = [&](size_t bytes) -> char* {
        char* p = base + off; off += (bytes + 255) & ~(size_t)255; return p;
    };
    w.flag    = (unsigned int*)take(256);
    w.cnt     = (unsigned int*)take((size_t)NSEG * 4);
    w.seg     = (unsigned int*)take((size_t)(NSEG + 1) * 4);
    w.skey    = (unsigned int*)take((size_t)N_EDGES * 4);
    w.sw      = (float*)take((size_t)N_EDGES * 4);
    w.Wt2     = (u16*)take((size_t)3 * 36 * 256 * 64 * 2);
    w.xc      = (u16*)take((size_t)N_NODES * 768 * 2);
    w.Hall    = (u16*)take((size_t)8 * cap * 256 * 2);
    w.p       = (float*)take((size_t)8 * N_NODES * 4);     // 640000 B
    w.score   = (float*)take((size_t)N_NODES * 4);         // 80000 B
    w.topidx  = (unsigned int*)take((size_t)NGRAPH * 256 * 4);
    w.topv    = (float*)take((size_t)NGRAPH * 256 * 4);
    w.readout = (float*)take((size_t)NGRAPH * 768 * 4);
    w.h1      = (float*)take((size_t)NGRAPH * 256 * 4);
    w.gx      = (float*)take((size_t)NGRAPH * 1024 * 4);
    w.whh4    = (unsigned int*)take((size_t)32 * 1024 * 4 * 4);
    w.parms   = (u16*)take((size_t)P_TOTAL * 2);
    // aliases: ctr (NSEG u32 = 640000 B) lives in p (same size); it is dead
    // before k_pool first writes p. bsum (4 KB) lives in score (80 KB); dead
    // before k_pool writes score. Both zero-regression on lifetimes.
    w.ctr  = (unsigned int*)w.p;
    w.bsum = (unsigned int*)w.score;
    w.need = off;
    return w;
}

extern "C" void kernel_launch(void* const* d_in, const int* in_sizes, int n_in,
                              void* d_out, int out_size, void* d_ws, size_t ws_size,
                              hipStream_t stream) {
    (void)in_sizes; (void)n_in; (void)out_size;
    const void* x        = d_in[0];
    const int* edge_index= (const int*)d_in[1];
    const int* edge_attr = (const int*)d_in[2];
    const void* conv_W   = d_in[4];
    const void* conv_root= d_in[5];
    const void* conv_bias= d_in[6];
    const void* pool_W   = d_in[7];
    const void* pool_root= d_in[8];
    const void* pool_bias= d_in[9];
    const void* fc1_W    = d_in[10];
    const void* fc1_b    = d_in[11];
    const void* W_ih     = d_in[12];
    const void* W_hh     = d_in[13];
    const void* b_ih     = d_in[14];
    const void* b_hh     = d_in[15];
    const void* fc2_W    = d_in[16];
    const void* fc2_b    = d_in[17];

    const int* e_src = edge_index;
    const int* e_dst = edge_index + N_EDGES;

    // chunk cap (multiple of NPG so chunks are whole graphs); unequal last chunk ok
    if (ws_size == 0) ws_size = (size_t)64 << 20;
    int cap = 500;
    {
        const int ladder[8] = {20000, 10000, 5000, 4000, 2500, 2000, 1000, 500};
        for (int i = 0; i < 8; ++i) {
            if (plan((char*)d_ws, ladder[i]).need <= ws_size) { cap = ladder[i]; break; }
        }
    }
    WS w = plan((char*)d_ws, cap);

    k_init<<<(NSEG + 255) / 256, 256, 0, stream>>>(w.flag, w.cnt, w.ctr);
    k_detect1<<<64, 256, 0, stream>>>((const u16*)x, 1 << 18, w.flag);
    k_count<<<1250, 256, 0, stream>>>(e_dst, edge_attr, w.cnt, w.flag);
    k_scan1<<<625, 256, 0, stream>>>(w.cnt, w.seg, w.bsum);
    k_scan2<<<1, 1024, 0, stream>>>(w.bsum, 625);
    k_scan3<<<(NSEG + 255) / 256, 256, 0, stream>>>(w.seg, w.bsum);
    k_place<<<1250, 256, 0, stream>>>(e_src, e_dst, edge_attr, w.seg, w.ctr, w.cnt,
                                      w.skey, w.sw, cap);

    k_prep<<<(PR_END + 255) / 256, 256, 0, stream>>>(
        conv_bias, pool_W, pool_root, pool_bias, fc1_W, fc1_b,
        W_ih, b_ih, b_hh, fc2_W, fc2_b,
        x, conv_W, conv_root, W_hh,
        w.parms, w.xc, w.Wt2, w.whh4, w.flag);

    for (int l = 0; l < 3; ++l) {
        const u16* xprev = w.xc + (l == 0 ? 512 : (l - 1) * 256);
        const u16* WtL = w.Wt2 + (size_t)l * 36 * 16384;
        const u16* bias = w.parms + P_CONV_BIAS + l * 256;
        for (int n0 = 0; n0 < N_NODES; n0 += cap) {
            int chnc = N_NODES - n0 < cap ? N_NODES - n0 : cap;
            int tiles = (chnc + 63) / 64;
            k_layer2<<<dim3(tiles, 9), 256, 0, stream>>>(xprev, WtL, w.Hall,
                                                         w.xc, l * 256, n0, chnc);
            k_gather<<<(chnc + 3) / 4, 256, 0, stream>>>(w.seg, w.skey, w.sw, w.Hall,
                                                         bias, w.xc, l * 256, n0, chnc);
        }
    }

    k_pool<<<5000, 256, 0, stream>>>(w.xc, w.parms, w.p, w.score);
    k_scatter_pool<<<1250, 256, 0, stream>>>(e_src, e_dst, edge_attr, w.cnt, w.p, w.score);
    k_sort<<<NGRAPH, 256, 0, stream>>>(w.score, w.topidx, w.topv);
    k_readout<<<dim3(NGRAPH, 12), 256, 0, stream>>>(w.topidx, w.topv, w.xc, w.readout);
    k_fc1<<<2560, 256, 0, stream>>>(w.readout, w.parms, w.h1);
    k_gx<<<10240, 256, 0, stream>>>(w.h1, w.parms, w.gx);
    k_lstm<<<1, 512, 0, stream>>>(w.gx, w.whh4, w.parms, d_out, w.flag);
}

// Round 12
// 678.081 us; speedup vs baseline: 1.5679x; 1.0070x over previous
//
#include <hip/hip_runtime.h>

typedef unsigned short u16;
typedef short bf8 __attribute__((ext_vector_type(8)));
typedef short bf4 __attribute__((ext_vector_type(4)));
typedef float f4 __attribute__((ext_vector_type(4)));
typedef _Float16 h2v __attribute__((ext_vector_type(2)));
typedef __fp16 g2v __attribute__((ext_vector_type(2)));
typedef unsigned int u4v __attribute__((ext_vector_type(4)));

#define N_NODES 20000
#define N_EDGES 320000
#define NGRAPH 40
#define NPG 500
#define KTOP 250
#define NSEG (N_NODES * 8)

// parms arena offsets (u16 elements)
#define P_CONV_BIAS 0
#define P_POOL_W    768
#define P_POOL_ROOT 6912
#define P_POOL_BIAS 7680
#define P_FC1_W     7688
#define P_FC1_B     204296
#define P_W_IH      204552
#define P_B_IH      466696
#define P_B_HH      467720
#define P_FC2_W     468744
#define P_FC2_B     469256
#define P_TOTAL     469264

// k_prep range boundaries (flat thread index)
#define PR_B0 469264                      // + P_TOTAL
#define PR_C0 (PR_B0 + 640000)            // + N_NODES*32 stage-x octets
#define PR_D0 (PR_C0 + 1769472)           // + 3*36*256*64 transpose elems
#define PR_END (PR_D0 + 131072)           // + 32*1024*4 whh4 elems

__device__ __forceinline__ float b2f(u16 u) {
    union { unsigned int i; float f; } v; v.i = ((unsigned int)u) << 16; return v.f;
}
__device__ __forceinline__ u16 f2b(float f) {
    union { float f; unsigned int i; } v; v.f = f;
    unsigned int x = v.i;
    return (u16)((x + 0x7fffu + ((x >> 16) & 1u)) >> 16);
}
__device__ __forceinline__ float wred(float s) {
    #pragma unroll
    for (int off = 32; off > 0; off >>= 1) s += __shfl_down(s, off);
    return s;
}
__device__ __forceinline__ float fdot2u(unsigned a, unsigned b, float c) {
#if __has_builtin(__builtin_amdgcn_fdot2)
    union { unsigned u; h2v h; } ua, ub; ua.u = a; ub.u = b;
    return __builtin_amdgcn_fdot2(ua.h, ub.h, c, false);
#else
    union { unsigned u; g2v h; } ua, ub; ua.u = a; ub.u = b;
    return c + (float)ua.h[0] * (float)ub.h[0] + (float)ua.h[1] * (float)ub.h[1];
#endif
}
__device__ __forceinline__ unsigned packh2(float a, float b) {
    g2v h = __builtin_amdgcn_cvt_pkrtz(a, b);
    union { g2v h; unsigned u; } v; v.h = h; return v.u;
}
// fast activations (v_exp based); |err| ~1e-6, far under output tolerance
__device__ __forceinline__ float sigm_f(float x) {
    return 1.0f / (1.0f + __expf(-x));
}
__device__ __forceinline__ float tanh_f(float x) {
    return 1.0f - 2.0f / (1.0f + __expf(2.0f * x));
}

// ---------------- init: zero flag + cnt + ctr ----------------
__global__ void k_init(unsigned int* __restrict__ flag, unsigned int* __restrict__ cnt,
                       unsigned int* __restrict__ ctr) {
    int i = blockIdx.x * 256 + threadIdx.x;
    if (i < 64) flag[i] = 0u;
    if (i < NSEG) { cnt[i] = 0u; ctr[i] = 0u; }
}

// ---------------- dtype detection (parallel) ----------------
__global__ void k_detect1(const u16* __restrict__ xr, int n, unsigned int* __restrict__ fb) {
    unsigned int local = 0;
    for (int i = blockIdx.x * 256 + threadIdx.x; i < n; i += 64 * 256) {
        unsigned int u = xr[i];
        if (((u >> 7) & 0xFFu) == 0xFFu) local++;
    }
    local = (unsigned int)wred((float)local);
    if ((threadIdx.x & 63) == 0 && local) atomicAdd(&fb[1], local);
}

__device__ __forceinline__ u16 load_cvt(const void* src, size_t i, bool f32) {
    return f32 ? f2b(((const float*)src)[i]) : ((const u16*)src)[i];
}

// ---------------- degree counts (+ flag finalize) ----------------
__global__ void k_count(const int* __restrict__ dst, const int* __restrict__ et,
                        unsigned int* __restrict__ cnt, unsigned int* __restrict__ fb) {
    int e = blockIdx.x * 256 + threadIdx.x;
    if (e == 0) fb[0] = (fb[1] > 8u) ? 1u : 0u;
    if (e < N_EDGES) {
        unsigned d = (unsigned)dst[e]; if (d >= N_NODES) d = 0;
        unsigned r = (unsigned)et[e] & 7u;
        atomicAdd(&cnt[d * 8 + r], 1u);
    }
}

// ---------------- prefix scan (exclusive) over cnt[160000] ----------------
__global__ void k_scan1(const unsigned int* __restrict__ cnt, unsigned int* __restrict__ seg,
                        unsigned int* __restrict__ bsum) {
    __shared__ unsigned int s[256];
    int t = threadIdx.x, i = blockIdx.x * 256 + t;
    unsigned int v = (i < NSEG) ? cnt[i] : 0u;
    s[t] = v;
    __syncthreads();
    for (int off = 1; off < 256; off <<= 1) {
        unsigned int add = (t >= off) ? s[t - off] : 0u;
        __syncthreads();
        s[t] += add;
        __syncthreads();
    }
    if (i < NSEG) seg[i] = s[t] - v;
    if (t == 255) bsum[blockIdx.x] = s[255];
}
__global__ void k_scan2(unsigned int* __restrict__ bsum, int nb) {
    __shared__ unsigned int s[1024];
    int t = threadIdx.x;
    unsigned int v = (t < nb) ? bsum[t] : 0u;
    s[t] = v;
    __syncthreads();
    for (int off = 1; off < 1024; off <<= 1) {
        unsigned int add = (t >= off) ? s[t - off] : 0u;
        __syncthreads();
        s[t] += add;
        __syncthreads();
    }
    if (t < nb) bsum[t] = s[t] - v;
}
__global__ void k_scan3(unsigned int* __restrict__ seg, const unsigned int* __restrict__ bsum) {
    int i = blockIdx.x * 256 + threadIdx.x;
    if (i < NSEG) seg[i] += bsum[i >> 8];
    if (i == 0) seg[NSEG] = N_EDGES;
}
// place edges into (dst,rel)-sorted order; skey = chunk-local src | (rel<<16)
__global__ void k_place(const int* __restrict__ src, const int* __restrict__ dst,
                        const int* __restrict__ et, const unsigned int* __restrict__ seg,
                        unsigned int* __restrict__ ctr, const unsigned int* __restrict__ cnt,
                        unsigned int* __restrict__ skey, float* __restrict__ sw, int cap) {
    int e = blockIdx.x * 256 + threadIdx.x;
    if (e >= N_EDGES) return;
    unsigned s = (unsigned)src[e]; if (s >= N_NODES) s = 0;
    unsigned d = (unsigned)dst[e]; if (d >= N_NODES) d = 0;
    unsigned r = (unsigned)et[e] & 7u;
    unsigned key = d * 8 + r;
    unsigned pos = seg[key] + atomicAdd(&ctr[key], 1u);
    unsigned base = (d / (unsigned)cap) * (unsigned)cap;   // chunks are whole graphs
    unsigned sl = s - base;
    if (sl >= (unsigned)cap) sl = 0u;            // defensive: keep in-bounds
    skey[pos] = sl | (r << 16);
    unsigned c = cnt[key];
    sw[pos] = 1.0f / (float)(c < 1u ? 1u : c);
}

// ---------------- fused one-shot prep: cvt_all | stage_x | transpose2 | whh4 -----
__global__ void k_prep(const void* conv_bias, const void* pool_W, const void* pool_root,
                       const void* pool_bias, const void* fc1_W, const void* fc1_b,
                       const void* W_ih, const void* b_ih, const void* b_hh,
                       const void* fc2_W, const void* fc2_b,
                       const void* __restrict__ x, const void* __restrict__ conv_W,
                       const void* __restrict__ conv_root, const void* __restrict__ W_hh,
                       u16* __restrict__ parms, u16* __restrict__ xc,
                       u16* __restrict__ Wt, unsigned int* __restrict__ whh4,
                       const unsigned int* __restrict__ flag) {
    int idx = blockIdx.x * 256 + threadIdx.x;
    bool f32 = (*flag != 0u);
    if (idx < PR_B0) {                                   // param canonicalization
        int i = idx;
        u16 v;
        if      (i < P_CONV_BIAS + 768)    v = load_cvt(conv_bias, i - P_CONV_BIAS, f32);
        else if (i < P_POOL_W + 6144)      v = load_cvt(pool_W,    i - P_POOL_W, f32);
        else if (i < P_POOL_ROOT + 768)    v = load_cvt(pool_root, i - P_POOL_ROOT, f32);
        else if (i < P_POOL_BIAS + 1)      v = load_cvt(pool_bias, i - P_POOL_BIAS, f32);
        else if (i < P_FC1_W && i >= P_POOL_BIAS) return;   // alignment gap
        else if (i < P_FC1_W + 196608)     v = load_cvt(fc1_W,    i - P_FC1_W, f32);
        else if (i < P_FC1_B + 256)        v = load_cvt(fc1_b,    i - P_FC1_B, f32);
        else if (i < P_W_IH + 262144)      v = load_cvt(W_ih,     i - P_W_IH, f32);
        else if (i < P_B_IH + 1024)        v = load_cvt(b_ih,     i - P_B_IH, f32);
        else if (i < P_B_HH + 1024)        v = load_cvt(b_hh,     i - P_B_HH, f32);
        else if (i < P_FC2_W + 512)        v = load_cvt(fc2_W,    i - P_FC2_W, f32);
        else if (i < P_FC2_B + 2)          v = load_cvt(fc2_b,    i - P_FC2_B, f32);
        else return;
        parms[i] = v;
    } else if (idx < PR_C0) {                            // stage x -> xc[:,512:768]
        int i = idx - PR_B0;
        int n = i >> 5, o = (i & 31) * 8;
        bf8 v;
        if (f32) {
            const float* s = (const float*)x + (size_t)n * 256 + o;
            #pragma unroll
            for (int c = 0; c < 8; ++c) v[c] = (short)f2b(s[c]);
        } else {
            v = *(const bf8*)((const u16*)x + (size_t)n * 256 + o);
        }
        *(bf8*)(xc + (size_t)n * 768 + 512 + o) = v;
    } else if (idx < PR_D0) {                            // conv weight transpose
        int i = idx - PR_C0;
        int kk = i & 63;
        int n = (i >> 6) & 255;
        int lc = i >> 14;            // l*36 + ck
        int l = lc / 36, ck = lc % 36;
        int k = ck * 64 + kk;
        u16 v;
        if (k < 2048) {
            int r = k >> 8, ii = k & 255;
            v = load_cvt(conv_W, ((size_t)((l * 8 + r) * 256 + ii)) * 256 + n, f32);
        } else {
            int ii = k - 2048;
            v = load_cvt(conv_root, ((size_t)(l * 256 + ii)) * 256 + n, f32);
        }
        Wt[i] = v;
    } else if (idx < PR_END) {                           // W_hh pack
        int i = idx - PR_D0;
        int c = i & 3, j = (i >> 2) & 1023, i4 = i >> 12;
        int i2 = i4 * 4 + c;
        float a, b;
        if (f32) {
            a = ((const float*)W_hh)[j * 256 + 2 * i2];
            b = ((const float*)W_hh)[j * 256 + 2 * i2 + 1];
        } else {
            a = b2f(((const u16*)W_hh)[j * 256 + 2 * i2]);
            b = b2f(((const u16*)W_hh)[j * 256 + 2 * i2 + 1]);
        }
        whh4[i] = packh2(a, b);
    }
}

// ---------------- dense per-relation transform over a node chunk ----------------
// Hall[rg][local][256] = X[n0+local] @ W_rg for rg=0..7; rg==8 (root) writes its
// pre-bias transform STRAIGHT INTO xc[:, colbase:+256] (gather reads it back and
// overwrites with the final value).
__launch_bounds__(256, 3)
__global__ void k_layer2(const u16* __restrict__ xprev,      // stride 768
                         const u16* __restrict__ WtL,        // [36][256][64]
                         u16* __restrict__ Hall,
                         u16* __restrict__ xcout, int colbase, int n0, int chnc) {
    __shared__ u16 As[64 * 264];
    int m0 = n0 + blockIdx.x * 64;
    int rg = blockIdx.y;
    int nend = n0 + chnc;
    int wave = threadIdx.x >> 6, lane = threadIdx.x & 63;
    int mrow = lane & 15, quad = lane >> 4;
    int nbase = wave * 64;

    // stage A tile [64][256] (dense, coalesced; zero-pad past chunk)
    {
        int row = threadIdx.x >> 2, sg = threadIdx.x & 3;
        int gm = m0 + row;
        u16* dstp = As + row * 264 + sg * 64;
        if (gm < nend) {
            const u16* srcp = xprev + (size_t)gm * 768 + sg * 64;
            #pragma unroll
            for (int c = 0; c < 8; ++c)
                *(bf8*)(dstp + c * 8) = *(const bf8*)(srcp + c * 8);
        } else {
            bf8 z = {0, 0, 0, 0, 0, 0, 0, 0};
            #pragma unroll
            for (int c = 0; c < 8; ++c) *(bf8*)(dstp + c * 8) = z;
        }
    }
    __syncthreads();

    f4 acc[4][4];
    #pragma unroll
    for (int nt = 0; nt < 4; ++nt)
        #pragma unroll
        for (int mh = 0; mh < 4; ++mh) acc[nt][mh] = (f4){0.0f, 0.0f, 0.0f, 0.0f};

    const u16* WtR = WtL + (size_t)(rg * 4) * 16384;   // ck = rg*4 + c4 (rg==8 -> root)
    #pragma unroll
    for (int c4 = 0; c4 < 4; ++c4) {
        const u16* Bck = WtR + (size_t)c4 * 16384;
        #pragma unroll
        for (int ks = 0; ks < 2; ++ks) {
            bf8 a[4];
            #pragma unroll
            for (int mh = 0; mh < 4; ++mh)
                a[mh] = *(const bf8*)(As + (mh * 16 + mrow) * 264 + c4 * 64 + ks * 32 + quad * 8);
            #pragma unroll
            for (int nt = 0; nt < 4; ++nt) {
                bf8 b = *(const bf8*)(Bck + (size_t)(nbase + nt * 16 + mrow) * 64
                                      + ks * 32 + quad * 8);
                #pragma unroll
                for (int mh = 0; mh < 4; ++mh)
                    acc[nt][mh] = __builtin_amdgcn_mfma_f32_16x16x32_bf16(a[mh], b, acc[nt][mh], 0, 0, 0);
            }
        }
    }

    // epilogue: restage to LDS ([64 m][256 n] stride 264), coalesced b128 store
    __syncthreads();
    #pragma unroll
    for (int nt = 0; nt < 4; ++nt) {
        int col = nbase + nt * 16 + mrow;
        #pragma unroll
        for (int mh = 0; mh < 4; ++mh)
            #pragma unroll
            for (int v = 0; v < 4; ++v)
                As[(mh * 16 + quad * 4 + v) * 264 + col] = f2b(acc[nt][mh][v]);
    }
    __syncthreads();
    {
        int row = threadIdx.x >> 2, sg = threadIdx.x & 3;
        int gm = m0 + row;
        if (gm < nend) {
            u16* dst = (rg < 8)
                ? Hall + ((size_t)rg * chnc + (gm - n0)) * 256 + sg * 64
                : xcout + (size_t)gm * 768 + colbase + sg * 64;
            const u16* srcp = As + row * 264 + sg * 64;
            #pragma unroll
            for (int c = 0; c < 8; ++c)
                *(bf8*)(dst + c * 8) = *(const bf8*)(srcp + c * 8);
        }
    }
}

// ---------------- edge gather over transformed features ----------------
__launch_bounds__(256)
__global__ void k_gather(const unsigned int* __restrict__ seg,
                         const unsigned int* __restrict__ skey,
                         const float* __restrict__ sw,
                         const u16* __restrict__ Hall,
                         const u16* __restrict__ bias,
                         u16* __restrict__ xc, int colbase, int n0, int chnc) {
    int nl = blockIdx.x * 4 + (threadIdx.x >> 6);
    if (nl >= chnc) return;
    int n = n0 + nl;
    int lane = threadIdx.x & 63;
    int c0 = lane * 4;
    unsigned e0 = seg[n * 8], e1 = seg[n * 8 + 8];
    float a0 = 0.0f, a1 = 0.0f, a2 = 0.0f, a3 = 0.0f;
    unsigned key = 0; float w = 0.0f;
    if (e0 < e1) { key = skey[e0]; w = sw[e0]; }
    for (unsigned e = e0; e < e1;) {
        unsigned kc = key; float wc = w;
        ++e;
        if (e < e1) { key = skey[e]; w = sw[e]; }   // prefetch next key while row load flies
        const u16* row = Hall + ((size_t)(kc >> 16) * chnc + (kc & 0xFFFFu)) * 256 + c0;
        bf4 v = *(const bf4*)row;
        a0 += wc * b2f((u16)v[0]);
        a1 += wc * b2f((u16)v[1]);
        a2 += wc * b2f((u16)v[2]);
        a3 += wc * b2f((u16)v[3]);
    }
    u16* xrow = xc + (size_t)n * 768 + colbase + c0;
    bf4 rv = *(const bf4*)xrow;                      // root transform (pre-bias)
    float o0 = a0 + b2f((u16)rv[0]) + b2f(bias[c0 + 0]);
    float o1 = a1 + b2f((u16)rv[1]) + b2f(bias[c0 + 1]);
    float o2 = a2 + b2f((u16)rv[2]) + b2f(bias[c0 + 2]);
    float o3 = a3 + b2f((u16)rv[3]) + b2f(bias[c0 + 3]);
    bf4 o;
    o[0] = (short)f2b(o0 > 0.0f ? o0 : 0.0f);
    o[1] = (short)f2b(o1 > 0.0f ? o1 : 0.0f);
    o[2] = (short)f2b(o2 > 0.0f ? o2 : 0.0f);
    o[3] = (short)f2b(o3 > 0.0f ? o3 : 0.0f);
    *(bf4*)xrow = o;
}

// ---------------- pool scorer: one wave per node, all 9 dots fused ----------------
__launch_bounds__(256)
__global__ void k_pool(const u16* __restrict__ xc, const u16* __restrict__ parms,
                       float* __restrict__ p, float* __restrict__ score) {
    int n = blockIdx.x * 4 + (threadIdx.x >> 6);
    if (n >= N_NODES) return;
    int lane = threadIdx.x & 63;
    const u16* xr = xc + (size_t)n * 768;
    float acc[9];
    #pragma unroll
    for (int rr = 0; rr < 9; ++rr) acc[rr] = 0.0f;
    #pragma unroll
    for (int q = 0; q < 12; ++q) {
        int f = lane + 64 * q;
        float xv = b2f(xr[f]);
        #pragma unroll
        for (int rr = 0; rr < 8; ++rr)
            acc[rr] += xv * b2f(parms[P_POOL_W + rr * 768 + f]);
        acc[8] += xv * b2f(parms[P_POOL_ROOT + f]);
    }
    #pragma unroll
    for (int rr = 0; rr < 9; ++rr) acc[rr] = wred(acc[rr]);
    if (lane == 0) {
        #pragma unroll
        for (int rr = 0; rr < 8; ++rr) p[rr * N_NODES + n] = acc[rr];
        score[n] = acc[8] + b2f(parms[P_POOL_BIAS]);
    }
}

// ---------------- pool scatter, atomic-free over sorted edges ----------------
// lane = (dst,rel) segment; 8-lane shfl_xor reduce across rels; single writer
// per dst adds into score (root part written by k_pool). Replaces 320K
// contended float atomics. Same math: sw is constant per segment = 1/cnt.
__launch_bounds__(256)
__global__ void k_score(const unsigned int* __restrict__ seg,
                        const unsigned int* __restrict__ skey,
                        const unsigned int* __restrict__ cnt,
                        const float* __restrict__ p, float* __restrict__ score, int cap) {
    int key = blockIdx.x * 256 + threadIdx.x;      // 625*256 == NSEG exactly
    int d = key >> 3, r = key & 7;
    unsigned base = ((unsigned)d / (unsigned)cap) * (unsigned)cap;
    unsigned e0 = seg[key], e1 = seg[key + 1];
    float s = 0.0f;
    for (unsigned e = e0; e < e1; ++e) {
        unsigned k2 = skey[e];
        s += p[(size_t)(k2 >> 16) * N_NODES + base + (k2 & 0xFFFFu)];
    }
    unsigned c = cnt[key];
    s *= 1.0f / (float)(c < 1u ? 1u : c);
    s += __shfl_xor(s, 1);
    s += __shfl_xor(s, 2);
    s += __shfl_xor(s, 4);
    if (r == 0) score[d] += s;                      // single writer per d
}

// ---------------- per-graph top-K sort ----------------
__launch_bounds__(256)
__global__ void k_sort(const float* __restrict__ score, unsigned int* __restrict__ topidx,
                       float* __restrict__ topv) {
    __shared__ unsigned long long keys[512];
    __shared__ float vals[512];
    int g = blockIdx.x, tid = threadIdx.x;
    for (int i = tid; i < 512; i += 256) {
        unsigned long long key;
        float v = 0.0f;
        if (i < NPG) {
            v = tanh_f(score[g * NPG + i]);
            unsigned int u = __float_as_uint(v);
            u = (u & 0x80000000u) ? ~u : (u | 0x80000000u);
            u = ~u;
            key = ((unsigned long long)u << 32) | (unsigned int)i;
        } else {
            key = 0xFFFFFFFFFFFFFFFFull;
        }
        keys[i] = key;
        vals[i] = v;
    }
    __syncthreads();
    for (int k = 2; k <= 512; k <<= 1)
        for (int j = k >> 1; j > 0; j >>= 1) {
            for (int i = tid; i < 512; i += 256) {
                int ixj = i ^ j;
                if (ixj > i) {
                    bool up = ((i & k) == 0);
                    unsigned long long a = keys[i], b = keys[ixj];
                    if ((a > b) == up) { keys[i] = b; keys[ixj] = a; }
                }
            }
            __syncthreads();
        }
    if (tid < KTOP) {
        int idx = (int)(keys[tid] & 511u);
        topidx[g * 256 + tid] = (unsigned)idx;
        topv[g * 256 + tid] = vals[idx];
    }
}

// ---------------- parallel weighted readout ----------------
__launch_bounds__(256)
__global__ void k_readout(const unsigned int* __restrict__ topidx,
                          const float* __restrict__ topv,
                          const u16* __restrict__ xc, float* __restrict__ readout) {
    __shared__ unsigned int sidx[KTOP];
    __shared__ float sv[KTOP];
    __shared__ float part[256];
    int g = blockIdx.x, cb = blockIdx.y;
    int tid = threadIdx.x;
    if (tid < KTOP) { sidx[tid] = topidx[g * 256 + tid]; sv[tid] = topv[g * 256 + tid]; }
    __syncthreads();
    int fl = tid & 63, ng = tid >> 6;
    int f = cb * 64 + fl;
    float acc = 0.0f;
    for (int j = ng; j < KTOP; j += 4)
        acc += sv[j] * b2f(xc[(size_t)(g * NPG + sidx[j]) * 768 + f]);
    part[tid] = acc;
    __syncthreads();
    if (tid < 64) {
        float s = part[tid] + part[64 + tid] + part[128 + tid] + part[192 + tid];
        readout[(size_t)g * 768 + cb * 64 + tid] = s * (1.0f / (float)KTOP);
    }
}

// ---------------- fc1 + LSTM input precompute ----------------
__global__ void k_fc1(const float* __restrict__ readout, const u16* __restrict__ parms,
                      float* __restrict__ h1) {
    int wid = blockIdx.x * 4 + (threadIdx.x >> 6);
    if (wid >= NGRAPH * 256) return;
    int g = wid >> 8, o = wid & 255, lane = threadIdx.x & 63;
    const float* rr = readout + (size_t)g * 768;
    const u16* w = parms + P_FC1_W + (size_t)o * 768;
    float s = 0.0f;
    #pragma unroll
    for (int q = 0; q < 12; ++q) { int f = lane + 64 * q; s += rr[f] * b2f(w[f]); }
    s = wred(s);
    if (lane == 0) { s += b2f(parms[P_FC1_B + o]); h1[g * 256 + o] = s > 0.0f ? s : 0.0f; }
}
__global__ void k_gx(const float* __restrict__ h1, const u16* __restrict__ parms,
                     float* __restrict__ gx) {
    int wid = blockIdx.x * 4 + (threadIdx.x >> 6);
    if (wid >= NGRAPH * 1024) return;
    int t = wid >> 10, j = wid & 1023, lane = threadIdx.x & 63;
    const float* xr = h1 + t * 256;
    const u16* w = parms + P_W_IH + (size_t)j * 256;
    float s = 0.0f;
    #pragma unroll
    for (int q = 0; q < 4; ++q) { int f = lane + 64 * q; s += xr[f] * b2f(w[f]); }
    s = wred(s);
    if (lane == 0) gx[t * 1024 + j] = s + b2f(parms[P_B_IH + j]) + b2f(parms[P_B_HH + j]);
}

// ---------------- sequential LSTM (r3 structure + readlane h-broadcast) ------
// r3 analysis update: VGPR=116 + zero scratch means the compiler already parks
// the 48 "pinned" chunks in AGPRs — weights ARE on-chip. Remaining per-step
// costs: q24-31 L2 stream, 96 scalar LDS broadcast reads of hs2, VALU, gates.
// This version removes the LDS-broadcast term: each thread keeps its lane's two
// packed-h words (hr0/hr1, refreshed with 2 LDS reads/step) and broadcasts via
// readlane (VALU, compile-time lane index; correctness field-tested in r8).
__launch_bounds__(512, 1)
__global__ void k_lstm(const float* __restrict__ gx, const unsigned int* __restrict__ whh4,
                       const u16* __restrict__ parms, void* __restrict__ out,
                       const unsigned int* __restrict__ flag) {
    __shared__ float hs[256];
    __shared__ unsigned int hs2[128];
    __shared__ float gs[1024];
    __shared__ float red[2];
    int tid = threadIdx.x;
    int j0 = tid, j1 = tid + 512;
    int lane = tid & 63;
    u4v wa[24], wb[24];
    #pragma unroll
    for (int q = 0; q < 24; ++q) {
        wa[q] = *(const u4v*)(whh4 + (((size_t)q * 1024) + j0) * 4);
        wb[q] = *(const u4v*)(whh4 + (((size_t)q * 1024) + j1) * 4);
    }
    asm volatile("" : "+v"(wa[0]), "+v"(wa[1]), "+v"(wa[2]), "+v"(wa[3]),
                      "+v"(wa[4]), "+v"(wa[5]), "+v"(wa[6]), "+v"(wa[7]),
                      "+v"(wa[8]), "+v"(wa[9]), "+v"(wa[10]), "+v"(wa[11]),
                      "+v"(wa[12]), "+v"(wa[13]), "+v"(wa[14]), "+v"(wa[15]),
                      "+v"(wa[16]), "+v"(wa[17]), "+v"(wa[18]), "+v"(wa[19]),
                      "+v"(wa[20]), "+v"(wa[21]), "+v"(wa[22]), "+v"(wa[23]));
    asm volatile("" : "+v"(wb[0]), "+v"(wb[1]), "+v"(wb[2]), "+v"(wb[3]),
                      "+v"(wb[4]), "+v"(wb[5]), "+v"(wb[6]), "+v"(wb[7]),
                      "+v"(wb[8]), "+v"(wb[9]), "+v"(wb[10]), "+v"(wb[11]),
                      "+v"(wb[12]), "+v"(wb[13]), "+v"(wb[14]), "+v"(wb[15]),
                      "+v"(wb[16]), "+v"(wb[17]), "+v"(wb[18]), "+v"(wb[19]),
                      "+v"(wb[20]), "+v"(wb[21]), "+v"(wb[22]), "+v"(wb[23]));
    if (tid < 256) hs[tid] = 0.0f;
    if (tid < 128) hs2[tid] = 0u;
    float c = 0.0f;
    int hr0 = 0, hr1 = 0;                         // this lane's packed h pairs
    __syncthreads();
    for (int t = 0; t < NGRAPH; ++t) {
        float g0 = gx[t * 1024 + j0];
        float g1 = gx[t * 1024 + j1];
        #pragma unroll
        for (int q = 0; q < 24; ++q) {
            #pragma unroll
            for (int cc = 0; cc < 4; ++cc) {
                int j = q * 4 + cc;
                unsigned h2 = (unsigned)__builtin_amdgcn_readlane(
                                  (j < 64) ? hr0 : hr1, j & 63);
                g0 = fdot2u(wa[q][cc], h2, g0);
                g1 = fdot2u(wb[q][cc], h2, g1);
            }
        }
        #pragma unroll 2
        for (int q = 24; q < 32; ++q) {
            u4v v0 = *(const u4v*)(whh4 + (((size_t)q * 1024) + j0) * 4);
            u4v v1 = *(const u4v*)(whh4 + (((size_t)q * 1024) + j1) * 4);
            #pragma unroll
            for (int cc = 0; cc < 4; ++cc) {
                unsigned h2 = (unsigned)__builtin_amdgcn_readlane(hr1, q * 4 + cc - 64);
                g0 = fdot2u(v0[cc], h2, g0);
                g1 = fdot2u(v1[cc], h2, g1);
            }
        }
        gs[j0] = g0;
        gs[j1] = g1;
        __syncthreads();
        if (tid < 256) {
            float gi = sigm_f(gs[tid]);
            float gf = sigm_f(gs[256 + tid]);
            float gg = tanh_f(gs[512 + tid]);
            float go = sigm_f(gs[768 + tid]);
            c = gf * c + gi * gg;
            float h = go * tanh_f(c);
            hs[tid] = h;
            float ho = __shfl(h, (tid & 63) ^ 1);
            if (!(tid & 1)) hs2[tid >> 1] = packh2(h, ho);
        }
        __syncthreads();
        hr0 = (int)hs2[lane];
        hr1 = (int)hs2[64 + lane];
    }
    if (tid < 128) {
        int cls = tid >> 6, l = tid & 63;
        float s = 0.0f;
        #pragma unroll
        for (int q = 0; q < 4; ++q) {
            int d = l + 64 * q;
            s += hs[d] * b2f(parms[P_FC2_W + cls * 256 + d]);
        }
        s = wred(s);
        if (l == 0) red[cls] = s + b2f(parms[P_FC2_B + cls]);
    }
    __syncthreads();
    if (tid == 0) {
        float l0 = red[0], l1 = red[1];
        float m = fmaxf(l0, l1);
        float lse = m + logf(expf(l0 - m) + expf(l1 - m));
        float o0 = l0 - lse, o1 = l1 - lse;
        if (*flag) { ((float*)out)[0] = o0; ((float*)out)[1] = o1; }
        else       { ((u16*)out)[0] = f2b(o0); ((u16*)out)[1] = f2b(o1); }
    }
}

// ---------------- workspace plan (Hall = 8 slices; ctr aliases p, bsum aliases score)
struct WS {
    unsigned int* flag; unsigned int* cnt; unsigned int* seg; unsigned int* ctr;
    unsigned int* skey; float* sw; unsigned int* bsum;
    u16* Wt2; u16* xc; u16* Hall; float* p; float* score;
    unsigned int* topidx; float* topv; float* readout; float* h1;
    float* gx; unsigned int* whh4; u16* parms;
    size_t need;
};
static WS plan(char* base, int cap) {
    WS w; size_t off = 0;
    auto take = [&](size_t bytes) -> char* {
        char* p = base + off; off += (bytes + 255) & ~(size_t)255; return p;
    };
    w.flag    = (unsigned int*)take(256);
    w.cnt     = (unsigned int*)take((size_t)NSEG * 4);
    w.seg     = (unsigned int*)take((size_t)(NSEG + 1) * 4);
    w.skey    = (unsigned int*)take((size_t)N_EDGES * 4);
    w.sw      = (float*)take((size_t)N_EDGES * 4);
    w.Wt2     = (u16*)take((size_t)3 * 36 * 256 * 64 * 2);
    w.xc      = (u16*)take((size_t)N_NODES * 768 * 2);
    w.Hall    = (u16*)take((size_t)8 * cap * 256 * 2);
    w.p       = (float*)take((size_t)8 * N_NODES * 4);     // 640000 B
    w.score   = (float*)take((size_t)N_NODES * 4);         // 80000 B
    w.topidx  = (unsigned int*)take((size_t)NGRAPH * 256 * 4);
    w.topv    = (float*)take((size_t)NGRAPH * 256 * 4);
    w.readout = (float*)take((size_t)NGRAPH * 768 * 4);
    w.h1      = (float*)take((size_t)NGRAPH * 256 * 4);
    w.gx      = (float*)take((size_t)NGRAPH * 1024 * 4);
    w.whh4    = (unsigned int*)take((size_t)32 * 1024 * 4 * 4);
    w.parms   = (u16*)take((size_t)P_TOTAL * 2);
    // aliases: ctr (NSEG u32 = 640000 B) lives in p (same size); dead before
    // k_pool writes p. bsum (4 KB) lives in score (80 KB); dead before k_pool
    // writes score.
    w.ctr  = (unsigned int*)w.p;
    w.bsum = (unsigned int*)w.score;
    w.need = off;
    return w;
}

extern "C" void kernel_launch(void* const* d_in, const int* in_sizes, int n_in,
                              void* d_out, int out_size, void* d_ws, size_t ws_size,
                              hipStream_t stream) {
    (void)in_sizes; (void)n_in; (void)out_size;
    const void* x        = d_in[0];
    const int* edge_index= (const int*)d_in[1];
    const int* edge_attr = (const int*)d_in[2];
    const void* conv_W   = d_in[4];
    const void* conv_root= d_in[5];
    const void* conv_bias= d_in[6];
    const void* pool_W   = d_in[7];
    const void* pool_root= d_in[8];
    const void* pool_bias= d_in[9];
    const void* fc1_W    = d_in[10];
    const void* fc1_b    = d_in[11];
    const void* W_ih     = d_in[12];
    const void* W_hh     = d_in[13];
    const void* b_ih     = d_in[14];
    const void* b_hh     = d_in[15];
    const void* fc2_W    = d_in[16];
    const void* fc2_b    = d_in[17];

    const int* e_src = edge_index;
    const int* e_dst = edge_index + N_EDGES;

    // chunk cap (multiple of NPG so chunks are whole graphs); unequal last chunk ok
    if (ws_size == 0) ws_size = (size_t)64 << 20;
    int cap = 500;
    {
        const int ladder[8] = {20000, 10000, 5000, 4000, 2500, 2000, 1000, 500};
        for (int i = 0; i < 8; ++i) {
            if (plan((char*)d_ws, ladder[i]).need <= ws_size) { cap = ladder[i]; break; }
        }
    }
    WS w = plan((char*)d_ws, cap);

    k_init<<<(NSEG + 255) / 256, 256, 0, stream>>>(w.flag, w.cnt, w.ctr);
    k_detect1<<<64, 256, 0, stream>>>((const u16*)x, 1 << 18, w.flag);
    k_count<<<1250, 256, 0, stream>>>(e_dst, edge_attr, w.cnt, w.flag);
    k_scan1<<<625, 256, 0, stream>>>(w.cnt, w.seg, w.bsum);
    k_scan2<<<1, 1024, 0, stream>>>(w.bsum, 625);
    k_scan3<<<(NSEG + 255) / 256, 256, 0, stream>>>(w.seg, w.bsum);
    k_place<<<1250, 256, 0, stream>>>(e_src, e_dst, edge_attr, w.seg, w.ctr, w.cnt,
                                      w.skey, w.sw, cap);

    k_prep<<<(PR_END + 255) / 256, 256, 0, stream>>>(
        conv_bias, pool_W, pool_root, pool_bias, fc1_W, fc1_b,
        W_ih, b_ih, b_hh, fc2_W, fc2_b,
        x, conv_W, conv_root, W_hh,
        w.parms, w.xc, w.Wt2, w.whh4, w.flag);

    for (int l = 0; l < 3; ++l) {
        const u16* xprev = w.xc + (l == 0 ? 512 : (l - 1) * 256);
        const u16* WtL = w.Wt2 + (size_t)l * 36 * 16384;
        const u16* bias = w.parms + P_CONV_BIAS + l * 256;
        for (int n0 = 0; n0 < N_NODES; n0 += cap) {
            int chnc = N_NODES - n0 < cap ? N_NODES - n0 : cap;
            int tiles = (chnc + 63) / 64;
            k_layer2<<<dim3(tiles, 9), 256, 0, stream>>>(xprev, WtL, w.Hall,
                                                         w.xc, l * 256, n0, chnc);
            k_gather<<<(chnc + 3) / 4, 256, 0, stream>>>(w.seg, w.skey, w.sw, w.Hall,
                                                         bias, w.xc, l * 256, n0, chnc);
        }
    }

    k_pool<<<5000, 256, 0, stream>>>(w.xc, w.parms, w.p, w.score);
    k_score<<<625, 256, 0, stream>>>(w.seg, w.skey, w.cnt, w.p, w.score, cap);
    k_sort<<<NGRAPH, 256, 0, stream>>>(w.score, w.topidx, w.topv);
    k_readout<<<dim3(NGRAPH, 12), 256, 0, stream>>>(w.topidx, w.topv, w.xc, w.readout);
    k_fc1<<<2560, 256, 0, stream>>>(w.readout, w.parms, w.h1);
    k_gx<<<10240, 256, 0, stream>>>(w.h1, w.parms, w.gx);
    k_lstm<<<1, 512, 0, stream>>>(w.gx, w.whh4, w.parms, d_out, w.flag);
}